// Round 12
// baseline (223.483 us; speedup 1.0000x reference)
//
#include <hip/hip_runtime.h>

typedef _Float16 f16;
typedef _Float16 f16x8 __attribute__((ext_vector_type(8)));
typedef float f32x4 __attribute__((ext_vector_type(4)));

#define MFMA16(a,b,c) __builtin_amdgcn_mfma_f32_16x16x32_f16((a),(b),(c),0,0,0)

__device__ __forceinline__ void gload16(const void* g, void* l) {
  __builtin_amdgcn_global_load_lds(
      (const __attribute__((address_space(1))) void*)g,
      (__attribute__((address_space(3))) void*)l, 16, 0, 0);
}

// swizzled f16 offset within a [rows][32 k] tile; c = 8-f16 chunk (0..3)
__device__ __forceinline__ int swz(int r, int c) {
  return r * 32 + ((c ^ (r & 3)) << 3);
}

// RTN split: v = hi + lo with hi = RTN f16
__device__ __forceinline__ void split8n(const f32x4 v0, const f32x4 v1,
                                        f16x8& hv, f16x8& lv) {
#pragma unroll
  for (int j = 0; j < 4; ++j) {
    f16 h0 = (f16)v0[j]; hv[j] = h0; lv[j] = (f16)(v0[j] - (float)h0);
    f16 h1 = (f16)v1[j]; hv[j + 4] = h1; lv[j + 4] = (f16)(v1[j] - (float)h1);
  }
}

// ---------- prep: f32 in[R][C] -> tiled+swizzled fp16 hi/lo tiles ----------
__global__ __launch_bounds__(256) void k_prep(const float* __restrict__ in,
                                              f16* __restrict__ oh, f16* __restrict__ ol,
                                              int R, int C, int trShift) {
  __shared__ float t[64][65];
  int c0 = blockIdx.x * 64, r0 = blockIdx.y * 64;
  int tid = threadIdx.x;
#pragma unroll
  for (int i = 0; i < 16; ++i) {
    int idx = tid + i * 256;
    int r = idx >> 6, c = idx & 63;
    t[r][c] = in[(size_t)(r0 + r) * C + (c0 + c)];
  }
  __syncthreads();
  int ktiles = R >> 5;
  int TRm1 = (1 << trShift) - 1;
#pragma unroll
  for (int w = 0; w < 2; ++w) {
    int idx = tid + w * 256;
    int nn = idx >> 3, cc8 = idx & 7;
    f32x4 v0, v1;
#pragma unroll
    for (int j = 0; j < 4; ++j) v0[j] = t[cc8 * 8 + j][nn];
#pragma unroll
    for (int j = 0; j < 4; ++j) v1[j] = t[cc8 * 8 + 4 + j][nn];
    f16x8 hv, lv;
    split8n(v0, v1, hv, lv);
    int gn = c0 + nn, gk = r0 + cc8 * 8;
    size_t tileIdx = (size_t)(gn >> trShift) * ktiles + (gk >> 5);
    size_t off = (tileIdx << (trShift + 5)) + ((size_t)(gn & TRm1) << 5) +
                 (((cc8 & 3) ^ (gn & 3)) << 3);
    *(f16x8*)&oh[off] = hv;
    *(f16x8*)&ol[off] = lv;
  }
}

// ---------- GEMM1 v8: 8-wave 128x256 tile, 4-phase, COUNTED waits (T4) ----------
// grid (64 bx, 8 kc), 512 thr. A: X f32 reg-staged + in-loop split -> 2-buf LDS;
// B: W1 TR=256 pre-tiled via gload_lds, 3-buf, distance-2 prefetch.
// No vmcnt drain in the loop: the compiler's precise wait for the A-reg split
// (A(t+1) issued BEFORE B(t+2)) retires B(t+1) while B(t+2) stays in flight.
__global__ __launch_bounds__(512, 1) void k_g1p8(
    const float* __restrict__ X, const f16* __restrict__ Bht,
    const f16* __restrict__ Blt, unsigned char* __restrict__ mb,
    float* __restrict__ partials) {
  __shared__ f16 smA[2][8192];   // [buf][hi 0..4095 | lo 4096..8191], 128m x 32k
  __shared__ f16 smB[3][16384];  // [buf][hi 0..8191 | lo 8192..16383], 256n x 32k
  int bx = blockIdx.x, kc = blockIdx.y;
  int tid = threadIdx.x;
  int wid = tid >> 6, ln = tid & 63, lr = ln & 15, lg = ln >> 4;
  int wr = wid >> 2, wc = wid & 3;  // 2M x 4N waves, each 64r x 64c
  const int NT = 16;
  int m0 = bx * 128, kb0 = kc * 512;

  // A staging: thread -> row arow, k-chunk (tid&3)*8
  int arow = tid >> 2, ac = tid & 3;
  const float* xA = X + (size_t)(m0 + arow) * 4096 + kb0 + ac * 8;
  int wa = swz(arow, ac);

  // B staging: 4 linear gload sweeps (tiles pre-swizzled at prep)
  size_t btile0 = (size_t)kc * 16 * 8192;
  auto stageB = [&](int t, int buf) {
    const f16* bh = Bht + btile0 + (size_t)t * 8192;
    const f16* bl = Blt + btile0 + (size_t)t * 8192;
    gload16(bh + (size_t)tid * 8, &smB[buf][wid * 512]);
    gload16(bh + 4096 + (size_t)tid * 8, &smB[buf][4096 + wid * 512]);
    gload16(bl + (size_t)tid * 8, &smB[buf][8192 + wid * 512]);
    gload16(bl + 4096 + (size_t)tid * 8, &smB[buf][8192 + 4096 + wid * 512]);
  };

  f32x4 acc[4][4] = {};
  f16x8 Ah[4], Al[4], Bh[4], Bl[4];
  f32x4 av0, av1;

#define MM3(i, j)                                      \
  do {                                                 \
    acc[i][j] = MFMA16(Ah[i], Bh[j], acc[i][j]);       \
    acc[i][j] = MFMA16(Ah[i], Bl[j], acc[i][j]);       \
    acc[i][j] = MFMA16(Al[i], Bh[j], acc[i][j]);       \
  } while (0)

  // ---- prologue: A(0) regs, B(0)->buf0, B(1)->buf1 ----
  {
    av0 = *(const f32x4*)xA;
    av1 = *(const f32x4*)(xA + 4);
    stageB(0, 0);
    stageB(1, 1);
    f16x8 h, l;
    split8n(av0, av1, h, l);
    *(f16x8*)&smA[0][wa] = h;
    *(f16x8*)&smA[0][4096 + wa] = l;
    unsigned m = 0;
#pragma unroll
    for (int j = 0; j < 4; ++j) {
      if (av0[j] != 0.f) m |= 1u << j;
      if (av1[j] != 0.f) m |= 1u << (4 + j);
    }
    mb[(size_t)(m0 + arow) * 512 + ((kb0 + ac * 8) >> 3)] = (unsigned char)m;
  }
  // B(0) complete, B(1) may stay in flight; drain own ds_writes
  asm volatile("s_waitcnt vmcnt(4) lgkmcnt(0)" ::: "memory");
  __builtin_amdgcn_s_barrier();

  int cb = 0;  // t % 3
  for (int t = 0; t < NT; ++t) {
    int cur = t & 1;
    bool moreA = (t + 1) < NT;
    bool moreB = (t + 2) < NT;
    const f16* A_ = &smA[cur][0];
    const f16* B_ = &smB[cb][0];

    // ---- P1: read A01 + B01; issue A(t+1) global loads (BEFORE B(t+2)) ----
#pragma unroll
    for (int i = 0; i < 2; ++i) {
      int r = wr * 64 + i * 16 + lr;
      Ah[i] = *(const f16x8*)&A_[swz(r, lg)];
      Al[i] = *(const f16x8*)&A_[4096 + swz(r, lg)];
      int c = wc * 64 + i * 16 + lr;
      Bh[i] = *(const f16x8*)&B_[swz(c, lg)];
      Bl[i] = *(const f16x8*)&B_[8192 + swz(c, lg)];
    }
    if (moreA) {
      const float* xp = xA + (t + 1) * 32;
      av0 = *(const f32x4*)xp;
      av1 = *(const f32x4*)(xp + 4);
    }
    __builtin_amdgcn_s_barrier();
    __builtin_amdgcn_s_setprio(1);
    MM3(0, 0); MM3(0, 1); MM3(1, 0); MM3(1, 1);
    __builtin_amdgcn_s_setprio(0);
    __builtin_amdgcn_s_barrier();

    // ---- P2: read B23; issue B(t+2) gloads ----
#pragma unroll
    for (int i = 2; i < 4; ++i) {
      int c = wc * 64 + i * 16 + lr;
      Bh[i] = *(const f16x8*)&B_[swz(c, lg)];
      Bl[i] = *(const f16x8*)&B_[8192 + swz(c, lg)];
    }
    if (moreB) {
      int pb = cb + 2; if (pb >= 3) pb -= 3;
      stageB(t + 2, pb);
    }
    __builtin_amdgcn_s_barrier();
    __builtin_amdgcn_s_setprio(1);
    MM3(0, 2); MM3(0, 3); MM3(1, 2); MM3(1, 3);
    __builtin_amdgcn_s_setprio(0);
    __builtin_amdgcn_s_barrier();

    // ---- P3: read A23; split A(t+1) (compiler waits vmcnt(4): retires B(t+1),
    //      keeps B(t+2) flying) + ds_write + mask ----
#pragma unroll
    for (int i = 2; i < 4; ++i) {
      int r = wr * 64 + i * 16 + lr;
      Ah[i] = *(const f16x8*)&A_[swz(r, lg)];
      Al[i] = *(const f16x8*)&A_[4096 + swz(r, lg)];
    }
    if (moreA) {
      f16x8 h, l;
      split8n(av0, av1, h, l);
      *(f16x8*)&smA[cur ^ 1][wa] = h;
      *(f16x8*)&smA[cur ^ 1][4096 + wa] = l;
      unsigned m = 0;
#pragma unroll
      for (int j = 0; j < 4; ++j) {
        if (av0[j] != 0.f) m |= 1u << j;
        if (av1[j] != 0.f) m |= 1u << (4 + j);
      }
      mb[(size_t)(m0 + arow) * 512 + ((kb0 + (t + 1) * 32 + ac * 8) >> 3)] =
          (unsigned char)m;
    }
    __builtin_amdgcn_s_barrier();
    __builtin_amdgcn_s_setprio(1);
    MM3(2, 0); MM3(2, 1); MM3(3, 0); MM3(3, 1);
    __builtin_amdgcn_s_setprio(0);
    __builtin_amdgcn_s_barrier();

    // ---- P4: final cluster; publish A ds_writes only (NO vmcnt drain) ----
    __builtin_amdgcn_s_setprio(1);
    MM3(2, 2); MM3(2, 3); MM3(3, 2); MM3(3, 3);
    __builtin_amdgcn_s_setprio(0);
    if (moreA) {
      asm volatile("s_waitcnt lgkmcnt(0)" ::: "memory");
      __builtin_amdgcn_s_barrier();
    }
    cb = cb + 1; if (cb >= 3) cb -= 3;
  }
#undef MM3

  float* pout = partials + (size_t)kc * 8192 * 256;
#pragma unroll
  for (int fi = 0; fi < 4; ++fi)
#pragma unroll
    for (int fj = 0; fj < 4; ++fj)
#pragma unroll
      for (int q = 0; q < 4; ++q) {
        int row = m0 + wr * 64 + fi * 16 + lg * 4 + q;
        int col = wc * 64 + fj * 16 + lr;
        pout[(size_t)row * 256 + col] = acc[fi][fj][q];
      }
}

// ---------- reduce split-K(8) + bias + relu + split -> tiled H hi/lo (TR=128) ----------
__global__ __launch_bounds__(256) void k_hsplit(const float* __restrict__ p,
                                                const float* __restrict__ b1,
                                                f16* __restrict__ Hh,
                                                f16* __restrict__ Hl) {
  int g = blockIdx.x * 256 + threadIdx.x;
  int r = g >> 5, c = g & 31;
  const size_t CH = (size_t)8192 * 256;
  const float* p0 = p + (size_t)r * 256 + c * 8;
  f32x4 s0 = *(const f32x4*)p0, s1 = *(const f32x4*)(p0 + 4);
#pragma unroll
  for (int q = 1; q < 8; ++q) {
    f32x4 d0 = *(const f32x4*)(p0 + q * CH), d1 = *(const f32x4*)(p0 + q * CH + 4);
#pragma unroll
    for (int j = 0; j < 4; ++j) { s0[j] += d0[j]; s1[j] += d1[j]; }
  }
  f32x4 bb0 = *(const f32x4*)(b1 + c * 8), bb1 = *(const f32x4*)(b1 + c * 8 + 4);
  f32x4 v0, v1;
#pragma unroll
  for (int j = 0; j < 4; ++j) {
    float v = s0[j] + bb0[j];
    v0[j] = v > 0.f ? v : 0.f;
    float w = s1[j] + bb1[j];
    v1[j] = w > 0.f ? w : 0.f;
  }
  f16x8 hv, lv;
  split8n(v0, v1, hv, lv);
  size_t tileIdx = (size_t)(r >> 7) * 8 + (c >> 2);
  size_t off = tileIdx * 4096 + ((size_t)(r & 127) << 5) + (((c & 3) ^ (r & 3)) << 3);
  *(f16x8*)&Hh[off] = hv;
  *(f16x8*)&Hl[off] = lv;
}

// ---------- GEMM2: 128x128 tile, F = H @ W2 + b2, masked f16 store + row sums ----------
__global__ __launch_bounds__(256, 2) void k_gemm2b(
    const f16* __restrict__ At_h, const f16* __restrict__ At_l,
    const f16* __restrict__ Bt_h, const f16* __restrict__ Bt_l,
    const float* __restrict__ b2, const unsigned* __restrict__ maskw,
    f16* __restrict__ fout, float* __restrict__ partials) {
  __shared__ f16 smA[2][2][4096];
  __shared__ f16 smB[2][2][4096];
  __shared__ unsigned mlds[128][4];
  __shared__ float rsum[128][2];
  int bx = blockIdx.x, by = blockIdx.y;
  int m0 = bx * 128, n0 = by * 128;
  int tid = threadIdx.x;
  int wv = tid >> 6, ln = tid & 63, lr = ln & 15, lg = ln >> 4;
  int wr = wv >> 1, wc = wv & 1;
#pragma unroll
  for (int i = 0; i < 2; ++i) {
    int idx = tid + i * 256;
    mlds[idx >> 2][idx & 3] =
        maskw[(size_t)(m0 + (idx >> 2)) * 128 + by * 4 + (idx & 3)];
  }
  size_t at0 = (size_t)bx * 8 * 4096;
  size_t bt0 = (size_t)by * 8 * 4096;

  auto stage = [&](int s, int buf) {
#pragma unroll
    for (int w = 0; w < 2; ++w) {
      size_t o = (size_t)(w * 4 + wv) * 512 + (size_t)ln * 8;
      gload16(At_h + at0 + (size_t)s * 4096 + o, &smA[buf][0][(w * 4 + wv) * 512]);
      gload16(At_l + at0 + (size_t)s * 4096 + o, &smA[buf][1][(w * 4 + wv) * 512]);
      gload16(Bt_h + bt0 + (size_t)s * 4096 + o, &smB[buf][0][(w * 4 + wv) * 512]);
      gload16(Bt_l + bt0 + (size_t)s * 4096 + o, &smB[buf][1][(w * 4 + wv) * 512]);
    }
  };

  f32x4 acc[4][4] = {};
  stage(0, 0);
  __syncthreads();
  int cur = 0;
  for (int s = 0; s < 8; ++s) {
    if (s + 1 < 8) stage(s + 1, cur ^ 1);
    f16x8 fah[4], fal[4], fbh[4], fbl[4];
#pragma unroll
    for (int f = 0; f < 4; ++f) {
      int r = wr * 64 + f * 16 + lr;
      fah[f] = *(const f16x8*)&smA[cur][0][swz(r, lg)];
      fal[f] = *(const f16x8*)&smA[cur][1][swz(r, lg)];
      int c = wc * 64 + f * 16 + lr;
      fbh[f] = *(const f16x8*)&smB[cur][0][swz(c, lg)];
      fbl[f] = *(const f16x8*)&smB[cur][1][swz(c, lg)];
    }
#pragma unroll
    for (int fi = 0; fi < 4; ++fi)
#pragma unroll
      for (int fj = 0; fj < 4; ++fj) {
        acc[fi][fj] = MFMA16(fah[fi], fbh[fj], acc[fi][fj]);
        acc[fi][fj] = MFMA16(fah[fi], fbl[fj], acc[fi][fj]);
        acc[fi][fj] = MFMA16(fal[fi], fbh[fj], acc[fi][fj]);
      }
    __syncthreads();
    cur ^= 1;
  }

  float rp[4][4] = {};
#pragma unroll
  for (int fi = 0; fi < 4; ++fi)
#pragma unroll
    for (int fj = 0; fj < 4; ++fj)
#pragma unroll
      for (int q = 0; q < 4; ++q) {
        int row = wr * 64 + fi * 16 + lg * 4 + q;
        int col = wc * 64 + fj * 16 + lr;
        float v = acc[fi][fj][q] + b2[n0 + col];
        unsigned wd = mlds[row][col >> 5];
        float mv = ((wd >> (col & 31)) & 1u) ? v : 0.f;
        fout[(size_t)(m0 + row) * 4096 + (n0 + col)] = (f16)mv;
        rp[fi][q] += mv;
      }
#pragma unroll
  for (int fi = 0; fi < 4; ++fi)
#pragma unroll
    for (int q = 0; q < 4; ++q) {
      float sv = rp[fi][q];
      sv += __shfl_xor(sv, 1);
      sv += __shfl_xor(sv, 2);
      sv += __shfl_xor(sv, 4);
      sv += __shfl_xor(sv, 8);
      if (lr == 0) rsum[wr * 64 + fi * 16 + lg * 4 + q][wc] = sv;
    }
  __syncthreads();
  if (tid < 128)
    partials[(size_t)(m0 + tid) * 32 + by] = rsum[tid][0] + rsum[tid][1];
}

// ---------- per-row inverse of masked sum ----------
__global__ __launch_bounds__(256) void k_rowinv(const float* __restrict__ partials,
                                                float* __restrict__ inv) {
  int r = blockIdx.x * 256 + threadIdx.x;
  if (r < 8192) {
    float s = 0.f;
#pragma unroll 4
    for (int i = 0; i < 32; ++i) s += partials[(size_t)r * 32 + i];
    float ss = (s == 0.f) ? 1.f : s;
    inv[r] = 1.f / ss;
  }
}

// ---------- scale: f16 f * inv -> f32 out ----------
__global__ __launch_bounds__(256) void k_scale16(const f16* __restrict__ f,
                                                 const float* __restrict__ inv,
                                                 float* __restrict__ out) {
  int v = blockIdx.x * 256 + threadIdx.x;
  float iv = inv[v >> 9];
  f16x8 d = *(const f16x8*)(f + (size_t)v * 8);
  f32x4 o0, o1;
#pragma unroll
  for (int j = 0; j < 4; ++j) {
    o0[j] = (float)d[j] * iv;
    o1[j] = (float)d[4 + j] * iv;
  }
  *(f32x4*)(out + (size_t)v * 8) = o0;
  *(f32x4*)(out + (size_t)v * 8 + 4) = o1;
}

extern "C" void kernel_launch(void* const* d_in, const int* in_sizes, int n_in,
                              void* d_out, int out_size, void* d_ws, size_t ws_size,
                              hipStream_t stream) {
  const float* x  = (const float*)d_in[0];
  const float* W1 = (const float*)d_in[1];
  const float* b1 = (const float*)d_in[2];
  const float* W2 = (const float*)d_in[3];
  const float* b2 = (const float*)d_in[4];
  float* out = (float*)d_out;
  char* ws = (char*)d_ws;

  const size_t MB = (size_t)1 << 20;
  f16* W1t_h = (f16*)(ws + 0 * MB);    // 2 MB, TR=256 tiles
  f16* W1t_l = (f16*)(ws + 2 * MB);
  f16* W2t_h = (f16*)(ws + 4 * MB);    // 2 MB, TR=128 tiles
  f16* W2t_l = (f16*)(ws + 6 * MB);
  f16* Hh    = (f16*)(ws + 8 * MB);    // 4 MB, TR=128 tiles
  f16* Hl    = (f16*)(ws + 12 * MB);
  unsigned char* mb = (unsigned char*)(ws + 16 * MB);  // 4 MB
  float* part1 = (float*)(ws + 20 * MB);   // 64 MB (8 x 8 MB split-K)
  float* part2 = (float*)(ws + 84 * MB);   // 1 MB [8192][32]
  float* inv_s = (float*)(ws + 85 * MB);   // 32 KB
  f16* fbuf    = (f16*)(ws + 86 * MB);     // 64 MB f16 f-buffer

  k_prep<<<dim3(4, 64), 256, 0, stream>>>(W1, W1t_h, W1t_l, 4096, 256, 8);
  k_prep<<<dim3(64, 4), 256, 0, stream>>>(W2, W2t_h, W2t_l, 256, 4096, 7);
  k_g1p8<<<dim3(64, 8), 512, 0, stream>>>(x, W1t_h, W1t_l, mb, part1);
  k_hsplit<<<1024, 256, 0, stream>>>(part1, b1, Hh, Hl);
  k_gemm2b<<<dim3(64, 32), 256, 0, stream>>>(Hh, Hl, W2t_h, W2t_l, b2,
                                             (const unsigned*)mb, fbuf, part2);
  k_rowinv<<<32, 256, 0, stream>>>(part2, inv_s);
  k_scale16<<<16384, 256, 0, stream>>>(fbuf, inv_s, out);
}

// Round 13
// 198.301 us; speedup vs baseline: 1.1270x; 1.1270x over previous
//
#include <hip/hip_runtime.h>

typedef _Float16 f16;
typedef _Float16 f16x8 __attribute__((ext_vector_type(8)));
typedef float f32x4 __attribute__((ext_vector_type(4)));

#define MFMA16(a,b,c) __builtin_amdgcn_mfma_f32_16x16x32_f16((a),(b),(c),0,0,0)

__device__ __forceinline__ void gload16(const void* g, void* l) {
  __builtin_amdgcn_global_load_lds(
      (const __attribute__((address_space(1))) void*)g,
      (__attribute__((address_space(3))) void*)l, 16, 0, 0);
}

// swizzled f16 offset within a [rows][32 k] tile; c = 8-f16 chunk (0..3)
__device__ __forceinline__ int swz(int r, int c) {
  return r * 32 + ((c ^ (r & 3)) << 3);
}

// RTN split: v = hi + lo with hi = RTN f16
__device__ __forceinline__ void split8n(const f32x4 v0, const f32x4 v1,
                                        f16x8& hv, f16x8& lv) {
#pragma unroll
  for (int j = 0; j < 4; ++j) {
    f16 h0 = (f16)v0[j]; hv[j] = h0; lv[j] = (f16)(v0[j] - (float)h0);
    f16 h1 = (f16)v1[j]; hv[j + 4] = h1; lv[j + 4] = (f16)(v1[j] - (float)h1);
  }
}

// ---------- prep: f32 in[R][C] -> tiled+swizzled fp16 hi/lo tiles ----------
__global__ __launch_bounds__(256) void k_prep(const float* __restrict__ in,
                                              f16* __restrict__ oh, f16* __restrict__ ol,
                                              int R, int C, int trShift) {
  __shared__ float t[64][65];
  int c0 = blockIdx.x * 64, r0 = blockIdx.y * 64;
  int tid = threadIdx.x;
#pragma unroll
  for (int i = 0; i < 16; ++i) {
    int idx = tid + i * 256;
    int r = idx >> 6, c = idx & 63;
    t[r][c] = in[(size_t)(r0 + r) * C + (c0 + c)];
  }
  __syncthreads();
  int ktiles = R >> 5;
  int TRm1 = (1 << trShift) - 1;
#pragma unroll
  for (int w = 0; w < 2; ++w) {
    int idx = tid + w * 256;
    int nn = idx >> 3, cc8 = idx & 7;
    f32x4 v0, v1;
#pragma unroll
    for (int j = 0; j < 4; ++j) v0[j] = t[cc8 * 8 + j][nn];
#pragma unroll
    for (int j = 0; j < 4; ++j) v1[j] = t[cc8 * 8 + 4 + j][nn];
    f16x8 hv, lv;
    split8n(v0, v1, hv, lv);
    int gn = c0 + nn, gk = r0 + cc8 * 8;
    size_t tileIdx = (size_t)(gn >> trShift) * ktiles + (gk >> 5);
    size_t off = (tileIdx << (trShift + 5)) + ((size_t)(gn & TRm1) << 5) +
                 (((cc8 & 3) ^ (gn & 3)) << 3);
    *(f16x8*)&oh[off] = hv;
    *(f16x8*)&ol[off] = lv;
  }
}

// ---------- GEMM1 v6b: 4 waves, each wave = DISTINCT 32 rows x 128 cols ----------
// A direct-from-global f32 + in-reg split (no LDS); B 3-buf LDS, counted vmcnt.
// grid (64 bx, 2 nb, 4 kc), 1024 k per block, NS=32 steps.
__global__ __launch_bounds__(256, 3) void k_g1(
    const float* __restrict__ X, const f16* __restrict__ Bht,
    const f16* __restrict__ Blt, unsigned char* __restrict__ mb,
    float* __restrict__ partials) {
  __shared__ f16 smB[3][8192];  // [buf][h 0..4095 | l 4096..8191], 128n x 32k
  int bx = blockIdx.x, nb = blockIdx.y, kc = blockIdx.z;
  int tid = threadIdx.x;
  int wv = tid >> 6, ln = tid & 63, lr = ln & 15, lg = ln >> 4;
  const int NS = 32;
  int m0 = bx * 128, kb0 = kc * 1024;
  size_t bt0 = ((size_t)nb * 128 + (size_t)kc * 32) * 4096;
  bool domask = (nb == 0);

  // lane's A rows: m0 + wv*32 + {0,16} + lr, k offset lg*8
  const float* xb = X + (size_t)(m0 + wv * 32 + lr) * 4096 + kb0 + lg * 8;
  const size_t XF = (size_t)16 * 4096;  // row-frag stride in floats

  f32x4 areg[4];
  f16x8 ah[2], al[2];
  f32x4 acc[2][8] = {};

  auto issueA = [&](int s) {
#pragma unroll
    for (int fi = 0; fi < 2; ++fi) {
      const float* p = xb + (size_t)fi * XF + s * 32;
      areg[fi * 2] = *(const f32x4*)p;
      areg[fi * 2 + 1] = *(const f32x4*)(p + 4);
    }
  };
  auto stageB = [&](int s, int buf) {
    const f16* bh = Bht + bt0 + (size_t)s * 4096;
    const f16* bl = Blt + bt0 + (size_t)s * 4096;
#pragma unroll
    for (int i = 0; i < 2; ++i)
      gload16(bh + ((i * 4 + wv) * 512 + ln * 8), &smB[buf][(i * 4 + wv) * 512]);
#pragma unroll
    for (int i = 0; i < 2; ++i)
      gload16(bl + ((i * 4 + wv) * 512 + ln * 8),
              &smB[buf][4096 + (i * 4 + wv) * 512]);
  };
  auto splitA = [&](int s) {
#pragma unroll
    for (int fi = 0; fi < 2; ++fi)
      split8n(areg[fi * 2], areg[fi * 2 + 1], ah[fi], al[fi]);
    if (domask) {
#pragma unroll
      for (int fi = 0; fi < 2; ++fi) {
        unsigned m = 0;
#pragma unroll
        for (int j = 0; j < 4; ++j) {
          if (areg[fi * 2][j] != 0.f) m |= 1u << j;
          if (areg[fi * 2 + 1][j] != 0.f) m |= 1u << (4 + j);
        }
        int row = m0 + wv * 32 + fi * 16 + lr;
        int gk = kb0 + s * 32 + lg * 8;
        mb[(size_t)row * 512 + (gk >> 3)] = (unsigned char)m;
      }
    }
  };

  // prologue: A(0) 4 + B(0) 4 + B(1) 4 = 12 outstanding; retire A(0)+B(0)
  issueA(0);
  stageB(0, 0);
  stageB(1, 1);
  asm volatile("s_waitcnt vmcnt(4)" ::: "memory");
  __builtin_amdgcn_sched_barrier(0);
  splitA(0);
  __builtin_amdgcn_s_barrier();

  int cb = 0;
  for (int s = 0; s < NS; ++s) {
    bool moreA = (s + 1) < NS;
    bool moreB = (s + 2) < NS;
    if (moreA) issueA(s + 1);
    if (moreB) {
      int pb = cb + 2; if (pb >= 3) pb -= 3;
      stageB(s + 2, pb);
    }
    // compute step s: two groups of 4 col-frags to cap live B regs
#pragma unroll
    for (int g = 0; g < 2; ++g) {
      f16x8 fbh[4], fbl[4];
#pragma unroll
      for (int j = 0; j < 4; ++j) {
        int c = (g * 4 + j) * 16 + lr;
        fbh[j] = *(const f16x8*)&smB[cb][swz(c, lg)];
        fbl[j] = *(const f16x8*)&smB[cb][4096 + swz(c, lg)];
      }
#pragma unroll
      for (int fi = 0; fi < 2; ++fi)
#pragma unroll
        for (int j = 0; j < 4; ++j) {
          acc[fi][g * 4 + j] = MFMA16(ah[fi], fbh[j], acc[fi][g * 4 + j]);
          acc[fi][g * 4 + j] = MFMA16(ah[fi], fbl[j], acc[fi][g * 4 + j]);
          acc[fi][g * 4 + j] = MFMA16(al[fi], fbh[j], acc[fi][g * 4 + j]);
        }
    }
    if (moreA) {
      if (moreB)
        asm volatile("s_waitcnt vmcnt(4)" ::: "memory");  // retire B(s+1)+A(s+1)
      else
        asm volatile("s_waitcnt vmcnt(0)" ::: "memory");
      __builtin_amdgcn_sched_barrier(0);
      splitA(s + 1);
      __builtin_amdgcn_s_barrier();
    }
    cb = cb + 1; if (cb >= 3) cb -= 3;
  }

  float* pout = partials + (size_t)kc * 8192 * 256;
#pragma unroll
  for (int fi = 0; fi < 2; ++fi)
#pragma unroll
    for (int fj = 0; fj < 8; ++fj)
#pragma unroll
      for (int q = 0; q < 4; ++q) {
        int row = m0 + wv * 32 + fi * 16 + lg * 4 + q;
        int col = nb * 128 + fj * 16 + lr;
        pout[(size_t)row * 256 + col] = acc[fi][fj][q];
      }
}

// ---------- reduce split-K(4) + bias + relu + split -> tiled H hi/lo (TR=128) ----------
__global__ __launch_bounds__(256) void k_hsplit(const float* __restrict__ p,
                                                const float* __restrict__ b1,
                                                f16* __restrict__ Hh,
                                                f16* __restrict__ Hl) {
  int g = blockIdx.x * 256 + threadIdx.x;
  int r = g >> 5, c = g & 31;
  const size_t CH = (size_t)8192 * 256;
  const float* p0 = p + (size_t)r * 256 + c * 8;
  f32x4 s0 = *(const f32x4*)p0, s1 = *(const f32x4*)(p0 + 4);
#pragma unroll
  for (int q = 1; q < 4; ++q) {
    f32x4 d0 = *(const f32x4*)(p0 + q * CH), d1 = *(const f32x4*)(p0 + q * CH + 4);
#pragma unroll
    for (int j = 0; j < 4; ++j) { s0[j] += d0[j]; s1[j] += d1[j]; }
  }
  f32x4 bb0 = *(const f32x4*)(b1 + c * 8), bb1 = *(const f32x4*)(b1 + c * 8 + 4);
  f32x4 v0, v1;
#pragma unroll
  for (int j = 0; j < 4; ++j) {
    float v = s0[j] + bb0[j];
    v0[j] = v > 0.f ? v : 0.f;
    float w = s1[j] + bb1[j];
    v1[j] = w > 0.f ? w : 0.f;
  }
  f16x8 hv, lv;
  split8n(v0, v1, hv, lv);
  size_t tileIdx = (size_t)(r >> 7) * 8 + (c >> 2);
  size_t off = tileIdx * 4096 + ((size_t)(r & 127) << 5) + (((c & 3) ^ (r & 3)) << 3);
  *(f16x8*)&Hh[off] = hv;
  *(f16x8*)&Hl[off] = lv;
}

// ---------- GEMM2: 128x128 tile, F = H @ W2 + b2, masked f16 store + row sums ----------
__global__ __launch_bounds__(256, 2) void k_gemm2b(
    const f16* __restrict__ At_h, const f16* __restrict__ At_l,
    const f16* __restrict__ Bt_h, const f16* __restrict__ Bt_l,
    const float* __restrict__ b2, const unsigned* __restrict__ maskw,
    f16* __restrict__ fout, float* __restrict__ partials) {
  __shared__ f16 smA[2][2][4096];
  __shared__ f16 smB[2][2][4096];
  __shared__ unsigned mlds[128][4];
  __shared__ float rsum[128][2];
  int bx = blockIdx.x, by = blockIdx.y;
  int m0 = bx * 128, n0 = by * 128;
  int tid = threadIdx.x;
  int wv = tid >> 6, ln = tid & 63, lr = ln & 15, lg = ln >> 4;
  int wr = wv >> 1, wc = wv & 1;
#pragma unroll
  for (int i = 0; i < 2; ++i) {
    int idx = tid + i * 256;
    mlds[idx >> 2][idx & 3] =
        maskw[(size_t)(m0 + (idx >> 2)) * 128 + by * 4 + (idx & 3)];
  }
  size_t at0 = (size_t)bx * 8 * 4096;
  size_t bt0 = (size_t)by * 8 * 4096;

  auto stage = [&](int s, int buf) {
#pragma unroll
    for (int w = 0; w < 2; ++w) {
      size_t o = (size_t)(w * 4 + wv) * 512 + (size_t)ln * 8;
      gload16(At_h + at0 + (size_t)s * 4096 + o, &smA[buf][0][(w * 4 + wv) * 512]);
      gload16(At_l + at0 + (size_t)s * 4096 + o, &smA[buf][1][(w * 4 + wv) * 512]);
      gload16(Bt_h + bt0 + (size_t)s * 4096 + o, &smB[buf][0][(w * 4 + wv) * 512]);
      gload16(Bt_l + bt0 + (size_t)s * 4096 + o, &smB[buf][1][(w * 4 + wv) * 512]);
    }
  };

  f32x4 acc[4][4] = {};
  stage(0, 0);
  __syncthreads();
  int cur = 0;
  for (int s = 0; s < 8; ++s) {
    if (s + 1 < 8) stage(s + 1, cur ^ 1);
    f16x8 fah[4], fal[4], fbh[4], fbl[4];
#pragma unroll
    for (int f = 0; f < 4; ++f) {
      int r = wr * 64 + f * 16 + lr;
      fah[f] = *(const f16x8*)&smA[cur][0][swz(r, lg)];
      fal[f] = *(const f16x8*)&smA[cur][1][swz(r, lg)];
      int c = wc * 64 + f * 16 + lr;
      fbh[f] = *(const f16x8*)&smB[cur][0][swz(c, lg)];
      fbl[f] = *(const f16x8*)&smB[cur][1][swz(c, lg)];
    }
#pragma unroll
    for (int fi = 0; fi < 4; ++fi)
#pragma unroll
      for (int fj = 0; fj < 4; ++fj) {
        acc[fi][fj] = MFMA16(fah[fi], fbh[fj], acc[fi][fj]);
        acc[fi][fj] = MFMA16(fah[fi], fbl[fj], acc[fi][fj]);
        acc[fi][fj] = MFMA16(fal[fi], fbh[fj], acc[fi][fj]);
      }
    __syncthreads();
    cur ^= 1;
  }

  float rp[4][4] = {};
#pragma unroll
  for (int fi = 0; fi < 4; ++fi)
#pragma unroll
    for (int fj = 0; fj < 4; ++fj)
#pragma unroll
      for (int q = 0; q < 4; ++q) {
        int row = wr * 64 + fi * 16 + lg * 4 + q;
        int col = wc * 64 + fj * 16 + lr;
        float v = acc[fi][fj][q] + b2[n0 + col];
        unsigned wd = mlds[row][col >> 5];
        float mv = ((wd >> (col & 31)) & 1u) ? v : 0.f;
        fout[(size_t)(m0 + row) * 4096 + (n0 + col)] = (f16)mv;
        rp[fi][q] += mv;
      }
#pragma unroll
  for (int fi = 0; fi < 4; ++fi)
#pragma unroll
    for (int q = 0; q < 4; ++q) {
      float sv = rp[fi][q];
      sv += __shfl_xor(sv, 1);
      sv += __shfl_xor(sv, 2);
      sv += __shfl_xor(sv, 4);
      sv += __shfl_xor(sv, 8);
      if (lr == 0) rsum[wr * 64 + fi * 16 + lg * 4 + q][wc] = sv;
    }
  __syncthreads();
  if (tid < 128)
    partials[(size_t)(m0 + tid) * 32 + by] = rsum[tid][0] + rsum[tid][1];
}

// ---------- per-row inverse of masked sum ----------
__global__ __launch_bounds__(256) void k_rowinv(const float* __restrict__ partials,
                                                float* __restrict__ inv) {
  int r = blockIdx.x * 256 + threadIdx.x;
  if (r < 8192) {
    float s = 0.f;
#pragma unroll 4
    for (int i = 0; i < 32; ++i) s += partials[(size_t)r * 32 + i];
    float ss = (s == 0.f) ? 1.f : s;
    inv[r] = 1.f / ss;
  }
}

// ---------- scale: f16 f * inv -> f32 out ----------
__global__ __launch_bounds__(256) void k_scale16(const f16* __restrict__ f,
                                                 const float* __restrict__ inv,
                                                 float* __restrict__ out) {
  int v = blockIdx.x * 256 + threadIdx.x;
  float iv = inv[v >> 9];
  f16x8 d = *(const f16x8*)(f + (size_t)v * 8);
  f32x4 o0, o1;
#pragma unroll
  for (int j = 0; j < 4; ++j) {
    o0[j] = (float)d[j] * iv;
    o1[j] = (float)d[4 + j] * iv;
  }
  *(f32x4*)(out + (size_t)v * 8) = o0;
  *(f32x4*)(out + (size_t)v * 8 + 4) = o1;
}

extern "C" void kernel_launch(void* const* d_in, const int* in_sizes, int n_in,
                              void* d_out, int out_size, void* d_ws, size_t ws_size,
                              hipStream_t stream) {
  const float* x  = (const float*)d_in[0];
  const float* W1 = (const float*)d_in[1];
  const float* b1 = (const float*)d_in[2];
  const float* W2 = (const float*)d_in[3];
  const float* b2 = (const float*)d_in[4];
  float* out = (float*)d_out;
  char* ws = (char*)d_ws;

  const size_t MB = (size_t)1 << 20;
  f16* W1t_h = (f16*)(ws + 0 * MB);    // 2 MB, TR=128 tiles
  f16* W1t_l = (f16*)(ws + 2 * MB);
  f16* W2t_h = (f16*)(ws + 4 * MB);    // 2 MB, TR=128 tiles
  f16* W2t_l = (f16*)(ws + 6 * MB);
  f16* Hh    = (f16*)(ws + 8 * MB);    // 4 MB, TR=128 tiles
  f16* Hl    = (f16*)(ws + 12 * MB);
  unsigned char* mb = (unsigned char*)(ws + 16 * MB);  // 4 MB
  float* part1 = (float*)(ws + 20 * MB);   // 32 MB (4 x 8 MB split-K)
  float* part2 = (float*)(ws + 52 * MB);   // 1 MB [8192][32]
  float* inv_s = (float*)(ws + 53 * MB);   // 32 KB
  f16* fbuf    = (f16*)(ws + 54 * MB);     // 64 MB f16 f-buffer

  k_prep<<<dim3(4, 64), 256, 0, stream>>>(W1, W1t_h, W1t_l, 4096, 256, 7);
  k_prep<<<dim3(64, 4), 256, 0, stream>>>(W2, W2t_h, W2t_l, 256, 4096, 7);
  k_g1<<<dim3(64, 2, 4), 256, 0, stream>>>(x, W1t_h, W1t_l, mb, part1);
  k_hsplit<<<1024, 256, 0, stream>>>(part1, b1, Hh, Hl);
  k_gemm2b<<<dim3(64, 32), 256, 0, stream>>>(Hh, Hl, W2t_h, W2t_l, b2,
                                             (const unsigned*)mb, fbuf, part2);
  k_rowinv<<<32, 256, 0, stream>>>(part2, inv_s);
  k_scale16<<<16384, 256, 0, stream>>>(fbuf, inv_s, out);
}

// Round 14
// 190.967 us; speedup vs baseline: 1.1703x; 1.0384x over previous
//
#include <hip/hip_runtime.h>

typedef _Float16 f16;
typedef _Float16 f16x8 __attribute__((ext_vector_type(8)));
typedef float f32x4 __attribute__((ext_vector_type(4)));

#define MFMA16(a,b,c) __builtin_amdgcn_mfma_f32_16x16x32_f16((a),(b),(c),0,0,0)

__device__ __forceinline__ void gload16(const void* g, void* l) {
  __builtin_amdgcn_global_load_lds(
      (const __attribute__((address_space(1))) void*)g,
      (__attribute__((address_space(3))) void*)l, 16, 0, 0);
}

// swizzled f16 offset within a [rows][32 k] tile; c = 8-f16 chunk (0..3)
__device__ __forceinline__ int swz(int r, int c) {
  return r * 32 + ((c ^ (r & 3)) << 3);
}

// RTN split: v = hi + lo with hi = RTN f16
__device__ __forceinline__ void split8n(const f32x4 v0, const f32x4 v1,
                                        f16x8& hv, f16x8& lv) {
#pragma unroll
  for (int j = 0; j < 4; ++j) {
    f16 h0 = (f16)v0[j]; hv[j] = h0; lv[j] = (f16)(v0[j] - (float)h0);
    f16 h1 = (f16)v1[j]; hv[j + 4] = h1; lv[j + 4] = (f16)(v1[j] - (float)h1);
  }
}

// ---------- prep: f32 in[R][C] -> tiled+swizzled fp16 hi/lo tiles ----------
__global__ __launch_bounds__(256) void k_prep(const float* __restrict__ in,
                                              f16* __restrict__ oh, f16* __restrict__ ol,
                                              int R, int C, int trShift) {
  __shared__ float t[64][65];
  int c0 = blockIdx.x * 64, r0 = blockIdx.y * 64;
  int tid = threadIdx.x;
#pragma unroll
  for (int i = 0; i < 16; ++i) {
    int idx = tid + i * 256;
    int r = idx >> 6, c = idx & 63;
    t[r][c] = in[(size_t)(r0 + r) * C + (c0 + c)];
  }
  __syncthreads();
  int ktiles = R >> 5;
  int TRm1 = (1 << trShift) - 1;
#pragma unroll
  for (int w = 0; w < 2; ++w) {
    int idx = tid + w * 256;
    int nn = idx >> 3, cc8 = idx & 7;
    f32x4 v0, v1;
#pragma unroll
    for (int j = 0; j < 4; ++j) v0[j] = t[cc8 * 8 + j][nn];
#pragma unroll
    for (int j = 0; j < 4; ++j) v1[j] = t[cc8 * 8 + 4 + j][nn];
    f16x8 hv, lv;
    split8n(v0, v1, hv, lv);
    int gn = c0 + nn, gk = r0 + cc8 * 8;
    size_t tileIdx = (size_t)(gn >> trShift) * ktiles + (gk >> 5);
    size_t off = (tileIdx << (trShift + 5)) + ((size_t)(gn & TRm1) << 5) +
                 (((cc8 & 3) ^ (gn & 3)) << 3);
    *(f16x8*)&oh[off] = hv;
    *(f16x8*)&ol[off] = lv;
  }
}

// ---------- GEMM1 v6b: 4 waves, each wave = DISTINCT 32 rows x 128 cols ----------
// A direct-from-global f32 + in-reg split (no LDS); B 3-buf LDS, counted vmcnt.
// grid (64 bx, 2 nb, 4 kc), 1024 k per block, NS=32 steps.
__global__ __launch_bounds__(256, 3) void k_g1(
    const float* __restrict__ X, const f16* __restrict__ Bht,
    const f16* __restrict__ Blt, unsigned char* __restrict__ mb,
    float* __restrict__ partials) {
  __shared__ f16 smB[3][8192];  // [buf][h 0..4095 | l 4096..8191], 128n x 32k
  int bx = blockIdx.x, nb = blockIdx.y, kc = blockIdx.z;
  int tid = threadIdx.x;
  int wv = tid >> 6, ln = tid & 63, lr = ln & 15, lg = ln >> 4;
  const int NS = 32;
  int m0 = bx * 128, kb0 = kc * 1024;
  size_t bt0 = ((size_t)nb * 128 + (size_t)kc * 32) * 4096;
  bool domask = (nb == 0);

  const float* xb = X + (size_t)(m0 + wv * 32 + lr) * 4096 + kb0 + lg * 8;
  const size_t XF = (size_t)16 * 4096;

  f32x4 areg[4];
  f16x8 ah[2], al[2];
  f32x4 acc[2][8] = {};

  auto issueA = [&](int s) {
#pragma unroll
    for (int fi = 0; fi < 2; ++fi) {
      const float* p = xb + (size_t)fi * XF + s * 32;
      areg[fi * 2] = *(const f32x4*)p;
      areg[fi * 2 + 1] = *(const f32x4*)(p + 4);
    }
  };
  auto stageB = [&](int s, int buf) {
    const f16* bh = Bht + bt0 + (size_t)s * 4096;
    const f16* bl = Blt + bt0 + (size_t)s * 4096;
#pragma unroll
    for (int i = 0; i < 2; ++i)
      gload16(bh + ((i * 4 + wv) * 512 + ln * 8), &smB[buf][(i * 4 + wv) * 512]);
#pragma unroll
    for (int i = 0; i < 2; ++i)
      gload16(bl + ((i * 4 + wv) * 512 + ln * 8),
              &smB[buf][4096 + (i * 4 + wv) * 512]);
  };
  auto splitA = [&](int s) {
#pragma unroll
    for (int fi = 0; fi < 2; ++fi)
      split8n(areg[fi * 2], areg[fi * 2 + 1], ah[fi], al[fi]);
    if (domask) {
#pragma unroll
      for (int fi = 0; fi < 2; ++fi) {
        unsigned m = 0;
#pragma unroll
        for (int j = 0; j < 4; ++j) {
          if (areg[fi * 2][j] != 0.f) m |= 1u << j;
          if (areg[fi * 2 + 1][j] != 0.f) m |= 1u << (4 + j);
        }
        int row = m0 + wv * 32 + fi * 16 + lr;
        int gk = kb0 + s * 32 + lg * 8;
        mb[(size_t)row * 512 + (gk >> 3)] = (unsigned char)m;
      }
    }
  };

  issueA(0);
  stageB(0, 0);
  stageB(1, 1);
  asm volatile("s_waitcnt vmcnt(4)" ::: "memory");
  __builtin_amdgcn_sched_barrier(0);
  splitA(0);
  __builtin_amdgcn_s_barrier();

  int cb = 0;
  for (int s = 0; s < NS; ++s) {
    bool moreA = (s + 1) < NS;
    bool moreB = (s + 2) < NS;
    if (moreA) issueA(s + 1);
    if (moreB) {
      int pb = cb + 2; if (pb >= 3) pb -= 3;
      stageB(s + 2, pb);
    }
#pragma unroll
    for (int g = 0; g < 2; ++g) {
      f16x8 fbh[4], fbl[4];
#pragma unroll
      for (int j = 0; j < 4; ++j) {
        int c = (g * 4 + j) * 16 + lr;
        fbh[j] = *(const f16x8*)&smB[cb][swz(c, lg)];
        fbl[j] = *(const f16x8*)&smB[cb][4096 + swz(c, lg)];
      }
#pragma unroll
      for (int fi = 0; fi < 2; ++fi)
#pragma unroll
        for (int j = 0; j < 4; ++j) {
          acc[fi][g * 4 + j] = MFMA16(ah[fi], fbh[j], acc[fi][g * 4 + j]);
          acc[fi][g * 4 + j] = MFMA16(ah[fi], fbl[j], acc[fi][g * 4 + j]);
          acc[fi][g * 4 + j] = MFMA16(al[fi], fbh[j], acc[fi][g * 4 + j]);
        }
    }
    if (moreA) {
      if (moreB)
        asm volatile("s_waitcnt vmcnt(4)" ::: "memory");
      else
        asm volatile("s_waitcnt vmcnt(0)" ::: "memory");
      __builtin_amdgcn_sched_barrier(0);
      splitA(s + 1);
      __builtin_amdgcn_s_barrier();
    }
    cb = cb + 1; if (cb >= 3) cb -= 3;
  }

  float* pout = partials + (size_t)kc * 8192 * 256;
#pragma unroll
  for (int fi = 0; fi < 2; ++fi)
#pragma unroll
    for (int fj = 0; fj < 8; ++fj)
#pragma unroll
      for (int q = 0; q < 4; ++q) {
        int row = m0 + wv * 32 + fi * 16 + lg * 4 + q;
        int col = nb * 128 + fj * 16 + lr;
        pout[(size_t)row * 256 + col] = acc[fi][fj][q];
      }
}

// ---------- reduce split-K(4) + bias + relu + split -> tiled H hi/lo (TR=256) ----------
__global__ __launch_bounds__(256) void k_hsplit(const float* __restrict__ p,
                                                const float* __restrict__ b1,
                                                f16* __restrict__ Hh,
                                                f16* __restrict__ Hl) {
  int g = blockIdx.x * 256 + threadIdx.x;
  int r = g >> 5, c = g & 31;
  const size_t CH = (size_t)8192 * 256;
  const float* p0 = p + (size_t)r * 256 + c * 8;
  f32x4 s0 = *(const f32x4*)p0, s1 = *(const f32x4*)(p0 + 4);
#pragma unroll
  for (int q = 1; q < 4; ++q) {
    f32x4 d0 = *(const f32x4*)(p0 + q * CH), d1 = *(const f32x4*)(p0 + q * CH + 4);
#pragma unroll
    for (int j = 0; j < 4; ++j) { s0[j] += d0[j]; s1[j] += d1[j]; }
  }
  f32x4 bb0 = *(const f32x4*)(b1 + c * 8), bb1 = *(const f32x4*)(b1 + c * 8 + 4);
  f32x4 v0, v1;
#pragma unroll
  for (int j = 0; j < 4; ++j) {
    float v = s0[j] + bb0[j];
    v0[j] = v > 0.f ? v : 0.f;
    float w = s1[j] + bb1[j];
    v1[j] = w > 0.f ? w : 0.f;
  }
  f16x8 hv, lv;
  split8n(v0, v1, hv, lv);
  // TR=256 tiles: tileIdx = (r>>8)*8 + k-tile, tile = [256 rows][32 k]
  size_t tileIdx = (size_t)(r >> 8) * 8 + (c >> 2);
  size_t off = tileIdx * 8192 + ((size_t)(r & 255) << 5) + (((c & 3) ^ (r & 3)) << 3);
  *(f16x8*)&Hh[off] = hv;
  *(f16x8*)&Hl[off] = lv;
}

// ---------- GEMM2c: 256x256 tile, 8 waves, F = H @ W2 + b2, masked f16 store ----------
// grid (32 bx, 16 by), 512 thr; wave = 64 rows x 128 cols (4M x 2N layout).
__global__ __launch_bounds__(512, 1) void k_gemm2c(
    const f16* __restrict__ At_h, const f16* __restrict__ At_l,
    const f16* __restrict__ Bt_h, const f16* __restrict__ Bt_l,
    const float* __restrict__ b2, const unsigned* __restrict__ maskw,
    f16* __restrict__ fout, float* __restrict__ partials) {
  __shared__ f16 smA[2][2][8192];  // [buf][h/l][256 rows x 32 k]
  __shared__ f16 smB[2][2][8192];
  __shared__ unsigned mlds[256][8];
  __shared__ float rsum[256][2];
  int bx = blockIdx.x, by = blockIdx.y;
  int m0 = bx * 256, n0 = by * 256;
  int tid = threadIdx.x;
  int wid = tid >> 6, ln = tid & 63, lr = ln & 15, lg = ln >> 4;
  int wr = wid >> 1, wc = wid & 1;  // wr 0..3 (64 rows), wc 0..1 (128 cols)
#pragma unroll
  for (int i = 0; i < 4; ++i) {
    int idx = tid + i * 512;  // 2048 words
    mlds[idx >> 3][idx & 7] =
        maskw[(size_t)(m0 + (idx >> 3)) * 128 + by * 8 + (idx & 7)];
  }
  size_t at0 = (size_t)bx * 8 * 8192;
  size_t bt0 = (size_t)by * 8 * 8192;

  auto stage = [&](int s, int buf) {
#pragma unroll
    for (int i = 0; i < 2; ++i) {
      size_t o = (size_t)(i * 8 + wid) * 512 + (size_t)ln * 8;
      gload16(At_h + at0 + (size_t)s * 8192 + o, &smA[buf][0][(i * 8 + wid) * 512]);
      gload16(At_l + at0 + (size_t)s * 8192 + o, &smA[buf][1][(i * 8 + wid) * 512]);
      gload16(Bt_h + bt0 + (size_t)s * 8192 + o, &smB[buf][0][(i * 8 + wid) * 512]);
      gload16(Bt_l + bt0 + (size_t)s * 8192 + o, &smB[buf][1][(i * 8 + wid) * 512]);
    }
  };

  f32x4 acc[4][8] = {};
  stage(0, 0);
  __syncthreads();
  int cur = 0;
  for (int s = 0; s < 8; ++s) {
    if (s + 1 < 8) stage(s + 1, cur ^ 1);
    f16x8 fah[4], fal[4];
#pragma unroll
    for (int f = 0; f < 4; ++f) {
      int r = wr * 64 + f * 16 + lr;
      fah[f] = *(const f16x8*)&smA[cur][0][swz(r, lg)];
      fal[f] = *(const f16x8*)&smA[cur][1][swz(r, lg)];
    }
#pragma unroll
    for (int g = 0; g < 2; ++g) {
      f16x8 fbh[4], fbl[4];
#pragma unroll
      for (int j = 0; j < 4; ++j) {
        int c = wc * 128 + (g * 4 + j) * 16 + lr;
        fbh[j] = *(const f16x8*)&smB[cur][0][swz(c, lg)];
        fbl[j] = *(const f16x8*)&smB[cur][1][swz(c, lg)];
      }
#pragma unroll
      for (int fi = 0; fi < 4; ++fi)
#pragma unroll
        for (int j = 0; j < 4; ++j) {
          acc[fi][g * 4 + j] = MFMA16(fah[fi], fbh[j], acc[fi][g * 4 + j]);
          acc[fi][g * 4 + j] = MFMA16(fah[fi], fbl[j], acc[fi][g * 4 + j]);
          acc[fi][g * 4 + j] = MFMA16(fal[fi], fbh[j], acc[fi][g * 4 + j]);
        }
    }
    __syncthreads();
    cur ^= 1;
  }

  float rp[4][4] = {};
#pragma unroll
  for (int fi = 0; fi < 4; ++fi)
#pragma unroll
    for (int fj = 0; fj < 8; ++fj)
#pragma unroll
      for (int q = 0; q < 4; ++q) {
        int row = wr * 64 + fi * 16 + lg * 4 + q;
        int col = wc * 128 + fj * 16 + lr;
        float v = acc[fi][fj][q] + b2[n0 + col];
        unsigned wd = mlds[row][col >> 5];
        float mv = ((wd >> (col & 31)) & 1u) ? v : 0.f;
        fout[(size_t)(m0 + row) * 4096 + (n0 + col)] = (f16)mv;
        rp[fi][q] += mv;
      }
#pragma unroll
  for (int fi = 0; fi < 4; ++fi)
#pragma unroll
    for (int q = 0; q < 4; ++q) {
      float sv = rp[fi][q];
      sv += __shfl_xor(sv, 1);
      sv += __shfl_xor(sv, 2);
      sv += __shfl_xor(sv, 4);
      sv += __shfl_xor(sv, 8);
      if (lr == 0) rsum[wr * 64 + fi * 16 + lg * 4 + q][wc] = sv;
    }
  __syncthreads();
  if (tid < 256)
    partials[(size_t)(m0 + tid) * 16 + by] = rsum[tid][0] + rsum[tid][1];
}

// ---------- per-row inverse of masked sum ----------
__global__ __launch_bounds__(256) void k_rowinv(const float* __restrict__ partials,
                                                float* __restrict__ inv) {
  int r = blockIdx.x * 256 + threadIdx.x;
  if (r < 8192) {
    float s = 0.f;
#pragma unroll 4
    for (int i = 0; i < 16; ++i) s += partials[(size_t)r * 16 + i];
    float ss = (s == 0.f) ? 1.f : s;
    inv[r] = 1.f / ss;
  }
}

// ---------- scale: f16 f * inv -> f32 out ----------
__global__ __launch_bounds__(256) void k_scale16(const f16* __restrict__ f,
                                                 const float* __restrict__ inv,
                                                 float* __restrict__ out) {
  int v = blockIdx.x * 256 + threadIdx.x;
  float iv = inv[v >> 9];
  f16x8 d = *(const f16x8*)(f + (size_t)v * 8);
  f32x4 o0, o1;
#pragma unroll
  for (int j = 0; j < 4; ++j) {
    o0[j] = (float)d[j] * iv;
    o1[j] = (float)d[4 + j] * iv;
  }
  *(f32x4*)(out + (size_t)v * 8) = o0;
  *(f32x4*)(out + (size_t)v * 8 + 4) = o1;
}

extern "C" void kernel_launch(void* const* d_in, const int* in_sizes, int n_in,
                              void* d_out, int out_size, void* d_ws, size_t ws_size,
                              hipStream_t stream) {
  const float* x  = (const float*)d_in[0];
  const float* W1 = (const float*)d_in[1];
  const float* b1 = (const float*)d_in[2];
  const float* W2 = (const float*)d_in[3];
  const float* b2 = (const float*)d_in[4];
  float* out = (float*)d_out;
  char* ws = (char*)d_ws;

  const size_t MB = (size_t)1 << 20;
  f16* W1t_h = (f16*)(ws + 0 * MB);    // 2 MB, TR=128 tiles (gemm1 B)
  f16* W1t_l = (f16*)(ws + 2 * MB);
  f16* W2t_h = (f16*)(ws + 4 * MB);    // 2 MB, TR=256 tiles (gemm2 B)
  f16* W2t_l = (f16*)(ws + 6 * MB);
  f16* Hh    = (f16*)(ws + 8 * MB);    // 4 MB, TR=256 tiles (gemm2 A)
  f16* Hl    = (f16*)(ws + 12 * MB);
  unsigned char* mb = (unsigned char*)(ws + 16 * MB);  // 4 MB
  float* part1 = (float*)(ws + 20 * MB);   // 32 MB (4 x 8 MB split-K)
  float* part2 = (float*)(ws + 52 * MB);   // 512 KB [8192][16]
  float* inv_s = (float*)(ws + 53 * MB);   // 32 KB
  f16* fbuf    = (f16*)(ws + 54 * MB);     // 64 MB f16 f-buffer

  k_prep<<<dim3(4, 64), 256, 0, stream>>>(W1, W1t_h, W1t_l, 4096, 256, 7);
  k_prep<<<dim3(64, 4), 256, 0, stream>>>(W2, W2t_h, W2t_l, 256, 4096, 8);
  k_g1<<<dim3(64, 2, 4), 256, 0, stream>>>(x, W1t_h, W1t_l, mb, part1);
  k_hsplit<<<1024, 256, 0, stream>>>(part1, b1, Hh, Hl);
  k_gemm2c<<<dim3(32, 16), 512, 0, stream>>>(Hh, Hl, W2t_h, W2t_l, b2,
                                             (const unsigned*)mb, fbuf, part2);
  k_rowinv<<<32, 256, 0, stream>>>(part2, inv_s);
  k_scale16<<<16384, 256, 0, stream>>>(fbuf, inv_s, out);
}

// Round 15
// 188.139 us; speedup vs baseline: 1.1879x; 1.0150x over previous
//
#include <hip/hip_runtime.h>

typedef _Float16 f16;
typedef _Float16 f16x8 __attribute__((ext_vector_type(8)));
typedef float f32x4 __attribute__((ext_vector_type(4)));

#define MFMA16(a,b,c) __builtin_amdgcn_mfma_f32_16x16x32_f16((a),(b),(c),0,0,0)

__device__ __forceinline__ void gload16(const void* g, void* l) {
  __builtin_amdgcn_global_load_lds(
      (const __attribute__((address_space(1))) void*)g,
      (__attribute__((address_space(3))) void*)l, 16, 0, 0);
}

// swizzled f16 offset within a [rows][32 k] tile; c = 8-f16 chunk (0..3).
// XOR with (r>>1)&3 so the 4 even rows of any 8-row group hit 4 distinct
// bank quads (old (r&3) left rows 0,4,8,12 on the same banks = 4-way conflict).
__device__ __forceinline__ int swz(int r, int c) {
  return r * 32 + ((c ^ ((r >> 1) & 3)) << 3);
}

// RTN split: v = hi + lo with hi = RTN f16
__device__ __forceinline__ void split8n(const f32x4 v0, const f32x4 v1,
                                        f16x8& hv, f16x8& lv) {
#pragma unroll
  for (int j = 0; j < 4; ++j) {
    f16 h0 = (f16)v0[j]; hv[j] = h0; lv[j] = (f16)(v0[j] - (float)h0);
    f16 h1 = (f16)v1[j]; hv[j + 4] = h1; lv[j + 4] = (f16)(v1[j] - (float)h1);
  }
}

// ---------- prep: f32 in[R][C] -> tiled+swizzled fp16 hi/lo tiles ----------
__global__ __launch_bounds__(256) void k_prep(const float* __restrict__ in,
                                              f16* __restrict__ oh, f16* __restrict__ ol,
                                              int R, int C, int trShift) {
  __shared__ float t[64][65];
  int c0 = blockIdx.x * 64, r0 = blockIdx.y * 64;
  int tid = threadIdx.x;
#pragma unroll
  for (int i = 0; i < 16; ++i) {
    int idx = tid + i * 256;
    int r = idx >> 6, c = idx & 63;
    t[r][c] = in[(size_t)(r0 + r) * C + (c0 + c)];
  }
  __syncthreads();
  int ktiles = R >> 5;
  int TRm1 = (1 << trShift) - 1;
#pragma unroll
  for (int w = 0; w < 2; ++w) {
    int idx = tid + w * 256;
    int nn = idx >> 3, cc8 = idx & 7;
    f32x4 v0, v1;
#pragma unroll
    for (int j = 0; j < 4; ++j) v0[j] = t[cc8 * 8 + j][nn];
#pragma unroll
    for (int j = 0; j < 4; ++j) v1[j] = t[cc8 * 8 + 4 + j][nn];
    f16x8 hv, lv;
    split8n(v0, v1, hv, lv);
    int gn = c0 + nn, gk = r0 + cc8 * 8;
    size_t tileIdx = (size_t)(gn >> trShift) * ktiles + (gk >> 5);
    size_t off = (tileIdx << (trShift + 5)) + ((size_t)(gn & TRm1) << 5) +
                 (((cc8 & 3) ^ ((gn >> 1) & 3)) << 3);
    *(f16x8*)&oh[off] = hv;
    *(f16x8*)&ol[off] = lv;
  }
}

// ---------- GEMM1 v6b: 4 waves, each wave = DISTINCT 32 rows x 128 cols ----------
// A direct-from-global f32 + in-reg split (no LDS); B 3-buf LDS, counted vmcnt.
// grid (64 bx, 2 nb, 4 kc), 1024 k per block, NS=32 steps.
__global__ __launch_bounds__(256, 3) void k_g1(
    const float* __restrict__ X, const f16* __restrict__ Bht,
    const f16* __restrict__ Blt, unsigned char* __restrict__ mb,
    float* __restrict__ partials) {
  __shared__ f16 smB[3][8192];  // [buf][h 0..4095 | l 4096..8191], 128n x 32k
  int bx = blockIdx.x, nb = blockIdx.y, kc = blockIdx.z;
  int tid = threadIdx.x;
  int wv = tid >> 6, ln = tid & 63, lr = ln & 15, lg = ln >> 4;
  const int NS = 32;
  int m0 = bx * 128, kb0 = kc * 1024;
  size_t bt0 = ((size_t)nb * 128 + (size_t)kc * 32) * 4096;
  bool domask = (nb == 0);

  const float* xb = X + (size_t)(m0 + wv * 32 + lr) * 4096 + kb0 + lg * 8;
  const size_t XF = (size_t)16 * 4096;

  f32x4 areg[4];
  f16x8 ah[2], al[2];
  f32x4 acc[2][8] = {};

  auto issueA = [&](int s) {
#pragma unroll
    for (int fi = 0; fi < 2; ++fi) {
      const float* p = xb + (size_t)fi * XF + s * 32;
      areg[fi * 2] = *(const f32x4*)p;
      areg[fi * 2 + 1] = *(const f32x4*)(p + 4);
    }
  };
  auto stageB = [&](int s, int buf) {
    const f16* bh = Bht + bt0 + (size_t)s * 4096;
    const f16* bl = Blt + bt0 + (size_t)s * 4096;
#pragma unroll
    for (int i = 0; i < 2; ++i)
      gload16(bh + ((i * 4 + wv) * 512 + ln * 8), &smB[buf][(i * 4 + wv) * 512]);
#pragma unroll
    for (int i = 0; i < 2; ++i)
      gload16(bl + ((i * 4 + wv) * 512 + ln * 8),
              &smB[buf][4096 + (i * 4 + wv) * 512]);
  };
  auto splitA = [&](int s) {
#pragma unroll
    for (int fi = 0; fi < 2; ++fi)
      split8n(areg[fi * 2], areg[fi * 2 + 1], ah[fi], al[fi]);
    if (domask) {
#pragma unroll
      for (int fi = 0; fi < 2; ++fi) {
        unsigned m = 0;
#pragma unroll
        for (int j = 0; j < 4; ++j) {
          if (areg[fi * 2][j] != 0.f) m |= 1u << j;
          if (areg[fi * 2 + 1][j] != 0.f) m |= 1u << (4 + j);
        }
        int row = m0 + wv * 32 + fi * 16 + lr;
        int gk = kb0 + s * 32 + lg * 8;
        mb[(size_t)row * 512 + (gk >> 3)] = (unsigned char)m;
      }
    }
  };

  issueA(0);
  stageB(0, 0);
  stageB(1, 1);
  asm volatile("s_waitcnt vmcnt(4)" ::: "memory");
  __builtin_amdgcn_sched_barrier(0);
  splitA(0);
  __builtin_amdgcn_s_barrier();

  int cb = 0;
  for (int s = 0; s < NS; ++s) {
    bool moreA = (s + 1) < NS;
    bool moreB = (s + 2) < NS;
    if (moreA) issueA(s + 1);
    if (moreB) {
      int pb = cb + 2; if (pb >= 3) pb -= 3;
      stageB(s + 2, pb);
    }
#pragma unroll
    for (int g = 0; g < 2; ++g) {
      f16x8 fbh[4], fbl[4];
#pragma unroll
      for (int j = 0; j < 4; ++j) {
        int c = (g * 4 + j) * 16 + lr;
        fbh[j] = *(const f16x8*)&smB[cb][swz(c, lg)];
        fbl[j] = *(const f16x8*)&smB[cb][4096 + swz(c, lg)];
      }
#pragma unroll
      for (int fi = 0; fi < 2; ++fi)
#pragma unroll
        for (int j = 0; j < 4; ++j) {
          acc[fi][g * 4 + j] = MFMA16(ah[fi], fbh[j], acc[fi][g * 4 + j]);
          acc[fi][g * 4 + j] = MFMA16(ah[fi], fbl[j], acc[fi][g * 4 + j]);
          acc[fi][g * 4 + j] = MFMA16(al[fi], fbh[j], acc[fi][g * 4 + j]);
        }
    }
    if (moreA) {
      if (moreB)
        asm volatile("s_waitcnt vmcnt(4)" ::: "memory");
      else
        asm volatile("s_waitcnt vmcnt(0)" ::: "memory");
      __builtin_amdgcn_sched_barrier(0);
      splitA(s + 1);
      __builtin_amdgcn_s_barrier();
    }
    cb = cb + 1; if (cb >= 3) cb -= 3;
  }

  float* pout = partials + (size_t)kc * 8192 * 256;
#pragma unroll
  for (int fi = 0; fi < 2; ++fi)
#pragma unroll
    for (int fj = 0; fj < 8; ++fj)
#pragma unroll
      for (int q = 0; q < 4; ++q) {
        int row = m0 + wv * 32 + fi * 16 + lg * 4 + q;
        int col = nb * 128 + fj * 16 + lr;
        pout[(size_t)row * 256 + col] = acc[fi][fj][q];
      }
}

// ---------- reduce split-K(4) + bias + relu + split -> tiled H hi/lo (TR=256) ----------
__global__ __launch_bounds__(256) void k_hsplit(const float* __restrict__ p,
                                                const float* __restrict__ b1,
                                                f16* __restrict__ Hh,
                                                f16* __restrict__ Hl) {
  int g = blockIdx.x * 256 + threadIdx.x;
  int r = g >> 5, c = g & 31;
  const size_t CH = (size_t)8192 * 256;
  const float* p0 = p + (size_t)r * 256 + c * 8;
  f32x4 s0 = *(const f32x4*)p0, s1 = *(const f32x4*)(p0 + 4);
#pragma unroll
  for (int q = 1; q < 4; ++q) {
    f32x4 d0 = *(const f32x4*)(p0 + q * CH), d1 = *(const f32x4*)(p0 + q * CH + 4);
#pragma unroll
    for (int j = 0; j < 4; ++j) { s0[j] += d0[j]; s1[j] += d1[j]; }
  }
  f32x4 bb0 = *(const f32x4*)(b1 + c * 8), bb1 = *(const f32x4*)(b1 + c * 8 + 4);
  f32x4 v0, v1;
#pragma unroll
  for (int j = 0; j < 4; ++j) {
    float v = s0[j] + bb0[j];
    v0[j] = v > 0.f ? v : 0.f;
    float w = s1[j] + bb1[j];
    v1[j] = w > 0.f ? w : 0.f;
  }
  f16x8 hv, lv;
  split8n(v0, v1, hv, lv);
  // TR=256 tiles: tileIdx = (r>>8)*8 + k-tile, tile = [256 rows][32 k]
  size_t tileIdx = (size_t)(r >> 8) * 8 + (c >> 2);
  size_t off = tileIdx * 8192 + ((size_t)(r & 255) << 5) +
               (((c & 3) ^ ((r >> 1) & 3)) << 3);
  *(f16x8*)&Hh[off] = hv;
  *(f16x8*)&Hl[off] = lv;
}

// ---------- GEMM2c: 256x256 tile, 8 waves, F = H @ W2 + b2, masked f16 store ----------
// grid (32 bx, 16 by), 512 thr; wave = 64 rows x 128 cols (4M x 2N layout).
__global__ __launch_bounds__(512, 1) void k_gemm2c(
    const f16* __restrict__ At_h, const f16* __restrict__ At_l,
    const f16* __restrict__ Bt_h, const f16* __restrict__ Bt_l,
    const float* __restrict__ b2, const unsigned* __restrict__ maskw,
    f16* __restrict__ fout, float* __restrict__ partials) {
  __shared__ f16 smA[2][2][8192];  // [buf][h/l][256 rows x 32 k]
  __shared__ f16 smB[2][2][8192];
  __shared__ unsigned mlds[256][8];
  __shared__ float rsum[256][2];
  int bx = blockIdx.x, by = blockIdx.y;
  int m0 = bx * 256, n0 = by * 256;
  int tid = threadIdx.x;
  int wid = tid >> 6, ln = tid & 63, lr = ln & 15, lg = ln >> 4;
  int wr = wid >> 1, wc = wid & 1;  // wr 0..3 (64 rows), wc 0..1 (128 cols)
#pragma unroll
  for (int i = 0; i < 4; ++i) {
    int idx = tid + i * 512;  // 2048 words
    mlds[idx >> 3][idx & 7] =
        maskw[(size_t)(m0 + (idx >> 3)) * 128 + by * 8 + (idx & 7)];
  }
  size_t at0 = (size_t)bx * 8 * 8192;
  size_t bt0 = (size_t)by * 8 * 8192;

  auto stage = [&](int s, int buf) {
#pragma unroll
    for (int i = 0; i < 2; ++i) {
      size_t o = (size_t)(i * 8 + wid) * 512 + (size_t)ln * 8;
      gload16(At_h + at0 + (size_t)s * 8192 + o, &smA[buf][0][(i * 8 + wid) * 512]);
      gload16(At_l + at0 + (size_t)s * 8192 + o, &smA[buf][1][(i * 8 + wid) * 512]);
      gload16(Bt_h + bt0 + (size_t)s * 8192 + o, &smB[buf][0][(i * 8 + wid) * 512]);
      gload16(Bt_l + bt0 + (size_t)s * 8192 + o, &smB[buf][1][(i * 8 + wid) * 512]);
    }
  };

  f32x4 acc[4][8] = {};
  stage(0, 0);
  __syncthreads();
  int cur = 0;
  for (int s = 0; s < 8; ++s) {
    if (s + 1 < 8) stage(s + 1, cur ^ 1);
    f16x8 fah[4], fal[4];
#pragma unroll
    for (int f = 0; f < 4; ++f) {
      int r = wr * 64 + f * 16 + lr;
      fah[f] = *(const f16x8*)&smA[cur][0][swz(r, lg)];
      fal[f] = *(const f16x8*)&smA[cur][1][swz(r, lg)];
    }
#pragma unroll
    for (int g = 0; g < 2; ++g) {
      f16x8 fbh[4], fbl[4];
#pragma unroll
      for (int j = 0; j < 4; ++j) {
        int c = wc * 128 + (g * 4 + j) * 16 + lr;
        fbh[j] = *(const f16x8*)&smB[cur][0][swz(c, lg)];
        fbl[j] = *(const f16x8*)&smB[cur][1][swz(c, lg)];
      }
#pragma unroll
      for (int fi = 0; fi < 4; ++fi)
#pragma unroll
        for (int j = 0; j < 4; ++j) {
          acc[fi][g * 4 + j] = MFMA16(fah[fi], fbh[j], acc[fi][g * 4 + j]);
          acc[fi][g * 4 + j] = MFMA16(fah[fi], fbl[j], acc[fi][g * 4 + j]);
          acc[fi][g * 4 + j] = MFMA16(fal[fi], fbh[j], acc[fi][g * 4 + j]);
        }
    }
    __syncthreads();
    cur ^= 1;
  }

  float rp[4][4] = {};
#pragma unroll
  for (int fi = 0; fi < 4; ++fi)
#pragma unroll
    for (int fj = 0; fj < 8; ++fj)
#pragma unroll
      for (int q = 0; q < 4; ++q) {
        int row = wr * 64 + fi * 16 + lg * 4 + q;
        int col = wc * 128 + fj * 16 + lr;
        float v = acc[fi][fj][q] + b2[n0 + col];
        unsigned wd = mlds[row][col >> 5];
        float mv = ((wd >> (col & 31)) & 1u) ? v : 0.f;
        fout[(size_t)(m0 + row) * 4096 + (n0 + col)] = (f16)mv;
        rp[fi][q] += mv;
      }
#pragma unroll
  for (int fi = 0; fi < 4; ++fi)
#pragma unroll
    for (int q = 0; q < 4; ++q) {
      float sv = rp[fi][q];
      sv += __shfl_xor(sv, 1);
      sv += __shfl_xor(sv, 2);
      sv += __shfl_xor(sv, 4);
      sv += __shfl_xor(sv, 8);
      if (lr == 0) rsum[wr * 64 + fi * 16 + lg * 4 + q][wc] = sv;
    }
  __syncthreads();
  if (tid < 256)
    partials[(size_t)(m0 + tid) * 16 + by] = rsum[tid][0] + rsum[tid][1];
}

// ---------- per-row inverse of masked sum ----------
__global__ __launch_bounds__(256) void k_rowinv(const float* __restrict__ partials,
                                                float* __restrict__ inv) {
  int r = blockIdx.x * 256 + threadIdx.x;
  if (r < 8192) {
    float s = 0.f;
#pragma unroll 4
    for (int i = 0; i < 16; ++i) s += partials[(size_t)r * 16 + i];
    float ss = (s == 0.f) ? 1.f : s;
    inv[r] = 1.f / ss;
  }
}

// ---------- scale: f16 f * inv -> f32 out ----------
__global__ __launch_bounds__(256) void k_scale16(const f16* __restrict__ f,
                                                 const float* __restrict__ inv,
                                                 float* __restrict__ out) {
  int v = blockIdx.x * 256 + threadIdx.x;
  float iv = inv[v >> 9];
  f16x8 d = *(const f16x8*)(f + (size_t)v * 8);
  f32x4 o0, o1;
#pragma unroll
  for (int j = 0; j < 4; ++j) {
    o0[j] = (float)d[j] * iv;
    o1[j] = (float)d[4 + j] * iv;
  }
  *(f32x4*)(out + (size_t)v * 8) = o0;
  *(f32x4*)(out + (size_t)v * 8 + 4) = o1;
}

extern "C" void kernel_launch(void* const* d_in, const int* in_sizes, int n_in,
                              void* d_out, int out_size, void* d_ws, size_t ws_size,
                              hipStream_t stream) {
  const float* x  = (const float*)d_in[0];
  const float* W1 = (const float*)d_in[1];
  const float* b1 = (const float*)d_in[2];
  const float* W2 = (const float*)d_in[3];
  const float* b2 = (const float*)d_in[4];
  float* out = (float*)d_out;
  char* ws = (char*)d_ws;

  const size_t MB = (size_t)1 << 20;
  f16* W1t_h = (f16*)(ws + 0 * MB);    // 2 MB, TR=128 tiles (gemm1 B)
  f16* W1t_l = (f16*)(ws + 2 * MB);
  f16* W2t_h = (f16*)(ws + 4 * MB);    // 2 MB, TR=256 tiles (gemm2 B)
  f16* W2t_l = (f16*)(ws + 6 * MB);
  f16* Hh    = (f16*)(ws + 8 * MB);    // 4 MB, TR=256 tiles (gemm2 A)
  f16* Hl    = (f16*)(ws + 12 * MB);
  unsigned char* mb = (unsigned char*)(ws + 16 * MB);  // 4 MB
  float* part1 = (float*)(ws + 20 * MB);   // 32 MB (4 x 8 MB split-K)
  float* part2 = (float*)(ws + 52 * MB);   // 512 KB [8192][16]
  float* inv_s = (float*)(ws + 53 * MB);   // 32 KB
  f16* fbuf    = (f16*)(ws + 54 * MB);     // 64 MB f16 f-buffer

  k_prep<<<dim3(4, 64), 256, 0, stream>>>(W1, W1t_h, W1t_l, 4096, 256, 7);
  k_prep<<<dim3(64, 4), 256, 0, stream>>>(W2, W2t_h, W2t_l, 256, 4096, 8);
  k_g1<<<dim3(64, 2, 4), 256, 0, stream>>>(x, W1t_h, W1t_l, mb, part1);
  k_hsplit<<<1024, 256, 0, stream>>>(part1, b1, Hh, Hl);
  k_gemm2c<<<dim3(32, 16), 512, 0, stream>>>(Hh, Hl, W2t_h, W2t_l, b2,
                                             (const unsigned*)mb, fbuf, part2);
  k_rowinv<<<32, 256, 0, stream>>>(part2, inv_s);
  k_scale16<<<16384, 256, 0, stream>>>(fbuf, inv_s, out);
}

// Round 16
// 187.445 us; speedup vs baseline: 1.1923x; 1.0037x over previous
//
#include <hip/hip_runtime.h>

typedef _Float16 f16;
typedef _Float16 f16x8 __attribute__((ext_vector_type(8)));
typedef float f32x4 __attribute__((ext_vector_type(4)));

#define MFMA16(a,b,c) __builtin_amdgcn_mfma_f32_16x16x32_f16((a),(b),(c),0,0,0)

__device__ __forceinline__ void gload16(const void* g, void* l) {
  __builtin_amdgcn_global_load_lds(
      (const __attribute__((address_space(1))) void*)g,
      (__attribute__((address_space(3))) void*)l, 16, 0, 0);
}

// swizzled f16 offset within a [rows][32 k] tile; c = 8-f16 chunk (0..3).
__device__ __forceinline__ int swz(int r, int c) {
  return r * 32 + ((c ^ ((r >> 1) & 3)) << 3);
}

// RTN split: v = hi + lo with hi = RTN f16
__device__ __forceinline__ void split8n(const f32x4 v0, const f32x4 v1,
                                        f16x8& hv, f16x8& lv) {
#pragma unroll
  for (int j = 0; j < 4; ++j) {
    f16 h0 = (f16)v0[j]; hv[j] = h0; lv[j] = (f16)(v0[j] - (float)h0);
    f16 h1 = (f16)v1[j]; hv[j + 4] = h1; lv[j + 4] = (f16)(v1[j] - (float)h1);
  }
}

// ---------- prep: f32 in[R][C] -> tiled+swizzled fp16 hi/lo tiles ----------
__global__ __launch_bounds__(256) void k_prep(const float* __restrict__ in,
                                              f16* __restrict__ oh, f16* __restrict__ ol,
                                              int R, int C, int trShift) {
  __shared__ float t[64][65];
  int c0 = blockIdx.x * 64, r0 = blockIdx.y * 64;
  int tid = threadIdx.x;
#pragma unroll
  for (int i = 0; i < 16; ++i) {
    int idx = tid + i * 256;
    int r = idx >> 6, c = idx & 63;
    t[r][c] = in[(size_t)(r0 + r) * C + (c0 + c)];
  }
  __syncthreads();
  int ktiles = R >> 5;
  int TRm1 = (1 << trShift) - 1;
#pragma unroll
  for (int w = 0; w < 2; ++w) {
    int idx = tid + w * 256;
    int nn = idx >> 3, cc8 = idx & 7;
    f32x4 v0, v1;
#pragma unroll
    for (int j = 0; j < 4; ++j) v0[j] = t[cc8 * 8 + j][nn];
#pragma unroll
    for (int j = 0; j < 4; ++j) v1[j] = t[cc8 * 8 + 4 + j][nn];
    f16x8 hv, lv;
    split8n(v0, v1, hv, lv);
    int gn = c0 + nn, gk = r0 + cc8 * 8;
    size_t tileIdx = (size_t)(gn >> trShift) * ktiles + (gk >> 5);
    size_t off = (tileIdx << (trShift + 5)) + ((size_t)(gn & TRm1) << 5) +
                 (((cc8 & 3) ^ ((gn >> 1) & 3)) << 3);
    *(f16x8*)&oh[off] = hv;
    *(f16x8*)&ol[off] = lv;
  }
}

// ---------- GEMM1 v7: BK=64 per phase (halved barrier count), 4 waves ----------
// A direct-from-global f32 + in-reg split; B 2-buf LDS (32KB/buf), dist-1.
// grid (64 bx, 2 nb, 4 kc), 1024 k per block, NS=16 steps of 64 k.
__global__ __launch_bounds__(256, 2) void k_g1(
    const float* __restrict__ X, const f16* __restrict__ Bht,
    const f16* __restrict__ Blt, unsigned char* __restrict__ mb,
    float* __restrict__ partials) {
  // [buf][h: kk0 0..4095, kk1 4096..8191 | l: 8192..16383]
  __shared__ f16 smB[2][16384];
  int bx = blockIdx.x, nb = blockIdx.y, kc = blockIdx.z;
  int tid = threadIdx.x;
  int wv = tid >> 6, ln = tid & 63, lr = ln & 15, lg = ln >> 4;
  const int NS = 16;
  int m0 = bx * 128, kb0 = kc * 1024;
  size_t bt0 = ((size_t)nb * 128 + (size_t)kc * 32) * 4096;  // f16 elems
  bool domask = (nb == 0);

  const float* xb = X + (size_t)(m0 + wv * 32 + lr) * 4096 + kb0 + lg * 8;
  const size_t XF = (size_t)16 * 4096;

  f32x4 areg[8];           // [fi][kk][2]
  f16x8 ah[2][2], al[2][2];  // [fi][kk]
  f32x4 acc[2][8] = {};

  auto issueA = [&](int s) {
#pragma unroll
    for (int fi = 0; fi < 2; ++fi)
#pragma unroll
      for (int kk = 0; kk < 2; ++kk) {
        const float* p = xb + (size_t)fi * XF + s * 64 + kk * 32;
        areg[fi * 4 + kk * 2] = *(const f32x4*)p;
        areg[fi * 4 + kk * 2 + 1] = *(const f32x4*)(p + 4);
      }
  };
  // stage 64-k step: 2 consecutive k-tiles (8192 f16 h + 8192 f16 l)
  auto stageB = [&](int s, int buf) {
    const f16* bh = Bht + bt0 + (size_t)s * 8192;
    const f16* bl = Blt + bt0 + (size_t)s * 8192;
#pragma unroll
    for (int i = 0; i < 4; ++i)
      gload16(bh + ((i * 4 + wv) * 512 + ln * 8), &smB[buf][(i * 4 + wv) * 512]);
#pragma unroll
    for (int i = 0; i < 4; ++i)
      gload16(bl + ((i * 4 + wv) * 512 + ln * 8),
              &smB[buf][8192 + (i * 4 + wv) * 512]);
  };
  auto splitA = [&](int s) {
#pragma unroll
    for (int fi = 0; fi < 2; ++fi)
#pragma unroll
      for (int kk = 0; kk < 2; ++kk)
        split8n(areg[fi * 4 + kk * 2], areg[fi * 4 + kk * 2 + 1],
                ah[fi][kk], al[fi][kk]);
    if (domask) {
#pragma unroll
      for (int fi = 0; fi < 2; ++fi)
#pragma unroll
        for (int kk = 0; kk < 2; ++kk) {
          const f32x4& a0 = areg[fi * 4 + kk * 2];
          const f32x4& a1 = areg[fi * 4 + kk * 2 + 1];
          unsigned m = 0;
#pragma unroll
          for (int j = 0; j < 4; ++j) {
            if (a0[j] != 0.f) m |= 1u << j;
            if (a1[j] != 0.f) m |= 1u << (4 + j);
          }
          int row = m0 + wv * 32 + fi * 16 + lr;
          int gk = kb0 + s * 64 + kk * 32 + lg * 8;
          mb[(size_t)row * 512 + (gk >> 3)] = (unsigned char)m;
        }
    }
  };

  // prologue
  issueA(0);
  stageB(0, 0);
  asm volatile("s_waitcnt vmcnt(0)" ::: "memory");
  __builtin_amdgcn_sched_barrier(0);
  splitA(0);
  __builtin_amdgcn_s_barrier();

  int cur = 0;
  for (int s = 0; s < NS; ++s) {
    bool more = (s + 1) < NS;
    if (more) {
      issueA(s + 1);
      stageB(s + 1, cur ^ 1);
    }
    // compute 64-k step from smB[cur]
#pragma unroll
    for (int kk = 0; kk < 2; ++kk)
#pragma unroll
      for (int g = 0; g < 2; ++g) {
        f16x8 fbh[4], fbl[4];
#pragma unroll
        for (int j = 0; j < 4; ++j) {
          int c = (g * 4 + j) * 16 + lr;
          fbh[j] = *(const f16x8*)&smB[cur][kk * 4096 + swz(c, lg)];
          fbl[j] = *(const f16x8*)&smB[cur][8192 + kk * 4096 + swz(c, lg)];
        }
#pragma unroll
        for (int fi = 0; fi < 2; ++fi)
#pragma unroll
          for (int j = 0; j < 4; ++j) {
            acc[fi][g * 4 + j] = MFMA16(ah[fi][kk], fbh[j], acc[fi][g * 4 + j]);
            acc[fi][g * 4 + j] = MFMA16(ah[fi][kk], fbl[j], acc[fi][g * 4 + j]);
            acc[fi][g * 4 + j] = MFMA16(al[fi][kk], fbh[j], acc[fi][g * 4 + j]);
          }
      }
    if (more) {
      asm volatile("s_waitcnt vmcnt(0)" ::: "memory");
      __builtin_amdgcn_sched_barrier(0);
      splitA(s + 1);
      __builtin_amdgcn_s_barrier();
    }
    cur ^= 1;
  }

  float* pout = partials + (size_t)kc * 8192 * 256;
#pragma unroll
  for (int fi = 0; fi < 2; ++fi)
#pragma unroll
    for (int fj = 0; fj < 8; ++fj)
#pragma unroll
      for (int q = 0; q < 4; ++q) {
        int row = m0 + wv * 32 + fi * 16 + lg * 4 + q;
        int col = nb * 128 + fj * 16 + lr;
        pout[(size_t)row * 256 + col] = acc[fi][fj][q];
      }
}

// ---------- reduce split-K(4) + bias + relu + split -> tiled H hi/lo (TR=256) ----------
__global__ __launch_bounds__(256) void k_hsplit(const float* __restrict__ p,
                                                const float* __restrict__ b1,
                                                f16* __restrict__ Hh,
                                                f16* __restrict__ Hl) {
  int g = blockIdx.x * 256 + threadIdx.x;
  int r = g >> 5, c = g & 31;
  const size_t CH = (size_t)8192 * 256;
  const float* p0 = p + (size_t)r * 256 + c * 8;
  f32x4 s0 = *(const f32x4*)p0, s1 = *(const f32x4*)(p0 + 4);
#pragma unroll
  for (int q = 1; q < 4; ++q) {
    f32x4 d0 = *(const f32x4*)(p0 + q * CH), d1 = *(const f32x4*)(p0 + q * CH + 4);
#pragma unroll
    for (int j = 0; j < 4; ++j) { s0[j] += d0[j]; s1[j] += d1[j]; }
  }
  f32x4 bb0 = *(const f32x4*)(b1 + c * 8), bb1 = *(const f32x4*)(b1 + c * 8 + 4);
  f32x4 v0, v1;
#pragma unroll
  for (int j = 0; j < 4; ++j) {
    float v = s0[j] + bb0[j];
    v0[j] = v > 0.f ? v : 0.f;
    float w = s1[j] + bb1[j];
    v1[j] = w > 0.f ? w : 0.f;
  }
  f16x8 hv, lv;
  split8n(v0, v1, hv, lv);
  size_t tileIdx = (size_t)(r >> 8) * 8 + (c >> 2);
  size_t off = tileIdx * 8192 + ((size_t)(r & 255) << 5) +
               (((c & 3) ^ ((r >> 1) & 3)) << 3);
  *(f16x8*)&Hh[off] = hv;
  *(f16x8*)&Hl[off] = lv;
}

// ---------- GEMM2c: 256x256 tile, 8 waves, F = H @ W2 + b2, masked f16 store ----------
__global__ __launch_bounds__(512, 1) void k_gemm2c(
    const f16* __restrict__ At_h, const f16* __restrict__ At_l,
    const f16* __restrict__ Bt_h, const f16* __restrict__ Bt_l,
    const float* __restrict__ b2, const unsigned* __restrict__ maskw,
    f16* __restrict__ fout, float* __restrict__ partials) {
  __shared__ f16 smA[2][2][8192];
  __shared__ f16 smB[2][2][8192];
  __shared__ unsigned mlds[256][8];
  __shared__ float rsum[256][2];
  int bx = blockIdx.x, by = blockIdx.y;
  int m0 = bx * 256, n0 = by * 256;
  int tid = threadIdx.x;
  int wid = tid >> 6, ln = tid & 63, lr = ln & 15, lg = ln >> 4;
  int wr = wid >> 1, wc = wid & 1;
#pragma unroll
  for (int i = 0; i < 4; ++i) {
    int idx = tid + i * 512;
    mlds[idx >> 3][idx & 7] =
        maskw[(size_t)(m0 + (idx >> 3)) * 128 + by * 8 + (idx & 7)];
  }
  size_t at0 = (size_t)bx * 8 * 8192;
  size_t bt0 = (size_t)by * 8 * 8192;

  auto stage = [&](int s, int buf) {
#pragma unroll
    for (int i = 0; i < 2; ++i) {
      size_t o = (size_t)(i * 8 + wid) * 512 + (size_t)ln * 8;
      gload16(At_h + at0 + (size_t)s * 8192 + o, &smA[buf][0][(i * 8 + wid) * 512]);
      gload16(At_l + at0 + (size_t)s * 8192 + o, &smA[buf][1][(i * 8 + wid) * 512]);
      gload16(Bt_h + bt0 + (size_t)s * 8192 + o, &smB[buf][0][(i * 8 + wid) * 512]);
      gload16(Bt_l + bt0 + (size_t)s * 8192 + o, &smB[buf][1][(i * 8 + wid) * 512]);
    }
  };

  f32x4 acc[4][8] = {};
  stage(0, 0);
  __syncthreads();
  int cur = 0;
  for (int s = 0; s < 8; ++s) {
    if (s + 1 < 8) stage(s + 1, cur ^ 1);
    f16x8 fah[4], fal[4];
#pragma unroll
    for (int f = 0; f < 4; ++f) {
      int r = wr * 64 + f * 16 + lr;
      fah[f] = *(const f16x8*)&smA[cur][0][swz(r, lg)];
      fal[f] = *(const f16x8*)&smA[cur][1][swz(r, lg)];
    }
#pragma unroll
    for (int g = 0; g < 2; ++g) {
      f16x8 fbh[4], fbl[4];
#pragma unroll
      for (int j = 0; j < 4; ++j) {
        int c = wc * 128 + (g * 4 + j) * 16 + lr;
        fbh[j] = *(const f16x8*)&smB[cur][0][swz(c, lg)];
        fbl[j] = *(const f16x8*)&smB[cur][1][swz(c, lg)];
      }
#pragma unroll
      for (int fi = 0; fi < 4; ++fi)
#pragma unroll
        for (int j = 0; j < 4; ++j) {
          acc[fi][g * 4 + j] = MFMA16(fah[fi], fbh[j], acc[fi][g * 4 + j]);
          acc[fi][g * 4 + j] = MFMA16(fah[fi], fbl[j], acc[fi][g * 4 + j]);
          acc[fi][g * 4 + j] = MFMA16(fal[fi], fbh[j], acc[fi][g * 4 + j]);
        }
    }
    __syncthreads();
    cur ^= 1;
  }

  float rp[4][4] = {};
#pragma unroll
  for (int fi = 0; fi < 4; ++fi)
#pragma unroll
    for (int fj = 0; fj < 8; ++fj)
#pragma unroll
      for (int q = 0; q < 4; ++q) {
        int row = wr * 64 + fi * 16 + lg * 4 + q;
        int col = wc * 128 + fj * 16 + lr;
        float v = acc[fi][fj][q] + b2[n0 + col];
        unsigned wd = mlds[row][col >> 5];
        float mv = ((wd >> (col & 31)) & 1u) ? v : 0.f;
        fout[(size_t)(m0 + row) * 4096 + (n0 + col)] = (f16)mv;
        rp[fi][q] += mv;
      }
#pragma unroll
  for (int fi = 0; fi < 4; ++fi)
#pragma unroll
    for (int q = 0; q < 4; ++q) {
      float sv = rp[fi][q];
      sv += __shfl_xor(sv, 1);
      sv += __shfl_xor(sv, 2);
      sv += __shfl_xor(sv, 4);
      sv += __shfl_xor(sv, 8);
      if (lr == 0) rsum[wr * 64 + fi * 16 + lg * 4 + q][wc] = sv;
    }
  __syncthreads();
  if (tid < 256)
    partials[(size_t)(m0 + tid) * 16 + by] = rsum[tid][0] + rsum[tid][1];
}

// ---------- scale: f16 f * (1/rowsum) -> f32 out; rowinv fused in-block ----------
// each block covers 2048 consecutive f16 = exactly half of one row
__global__ __launch_bounds__(256) void k_scale16(const f16* __restrict__ f,
                                                 const float* __restrict__ partials,
                                                 float* __restrict__ out) {
  __shared__ float sinv;
  int tid = threadIdx.x;
  int row = blockIdx.x >> 1;
  if (tid == 0) {
    float s = 0.f;
#pragma unroll
    for (int i = 0; i < 16; ++i) s += partials[(size_t)row * 16 + i];
    sinv = 1.f / ((s == 0.f) ? 1.f : s);
  }
  __syncthreads();
  float iv = sinv;
  size_t v = (size_t)blockIdx.x * 256 + tid;
  f16x8 d = *(const f16x8*)(f + v * 8);
  f32x4 o0, o1;
#pragma unroll
  for (int j = 0; j < 4; ++j) {
    o0[j] = (float)d[j] * iv;
    o1[j] = (float)d[4 + j] * iv;
  }
  *(f32x4*)(out + v * 8) = o0;
  *(f32x4*)(out + v * 8 + 4) = o1;
}

extern "C" void kernel_launch(void* const* d_in, const int* in_sizes, int n_in,
                              void* d_out, int out_size, void* d_ws, size_t ws_size,
                              hipStream_t stream) {
  const float* x  = (const float*)d_in[0];
  const float* W1 = (const float*)d_in[1];
  const float* b1 = (const float*)d_in[2];
  const float* W2 = (const float*)d_in[3];
  const float* b2 = (const float*)d_in[4];
  float* out = (float*)d_out;
  char* ws = (char*)d_ws;

  const size_t MB = (size_t)1 << 20;
  f16* W1t_h = (f16*)(ws + 0 * MB);    // 2 MB, TR=128 tiles (gemm1 B)
  f16* W1t_l = (f16*)(ws + 2 * MB);
  f16* W2t_h = (f16*)(ws + 4 * MB);    // 2 MB, TR=256 tiles (gemm2 B)
  f16* W2t_l = (f16*)(ws + 6 * MB);
  f16* Hh    = (f16*)(ws + 8 * MB);    // 4 MB, TR=256 tiles (gemm2 A)
  f16* Hl    = (f16*)(ws + 12 * MB);
  unsigned char* mb = (unsigned char*)(ws + 16 * MB);  // 4 MB
  float* part1 = (float*)(ws + 20 * MB);   // 32 MB (4 x 8 MB split-K)
  float* part2 = (float*)(ws + 52 * MB);   // 512 KB [8192][16]
  f16* fbuf    = (f16*)(ws + 54 * MB);     // 64 MB f16 f-buffer

  k_prep<<<dim3(4, 64), 256, 0, stream>>>(W1, W1t_h, W1t_l, 4096, 256, 7);
  k_prep<<<dim3(64, 4), 256, 0, stream>>>(W2, W2t_h, W2t_l, 256, 4096, 8);
  k_g1<<<dim3(64, 2, 4), 256, 0, stream>>>(x, W1t_h, W1t_l, mb, part1);
  k_hsplit<<<1024, 256, 0, stream>>>(part1, b1, Hh, Hl);
  k_gemm2c<<<dim3(32, 16), 512, 0, stream>>>(Hh, Hl, W2t_h, W2t_l, b2,
                                             (const unsigned*)mb, fbuf, part2);
  k_scale16<<<16384, 256, 0, stream>>>(fbuf, part2, out);
}

// Round 17
// 185.243 us; speedup vs baseline: 1.2064x; 1.0119x over previous
//
#include <hip/hip_runtime.h>

typedef _Float16 f16;
typedef _Float16 f16x8 __attribute__((ext_vector_type(8)));
typedef float f32x4 __attribute__((ext_vector_type(4)));

#define MFMA16(a,b,c) __builtin_amdgcn_mfma_f32_16x16x32_f16((a),(b),(c),0,0,0)

__device__ __forceinline__ void gload16(const void* g, void* l) {
  __builtin_amdgcn_global_load_lds(
      (const __attribute__((address_space(1))) void*)g,
      (__attribute__((address_space(3))) void*)l, 16, 0, 0);
}

// swizzled f16 offset within a [rows][32 k] tile; c = 8-f16 chunk (0..3).
__device__ __forceinline__ int swz(int r, int c) {
  return r * 32 + ((c ^ ((r >> 1) & 3)) << 3);
}

// RTN split: v = hi + lo with hi = RTN f16
__device__ __forceinline__ void split8n(const f32x4 v0, const f32x4 v1,
                                        f16x8& hv, f16x8& lv) {
#pragma unroll
  for (int j = 0; j < 4; ++j) {
    f16 h0 = (f16)v0[j]; hv[j] = h0; lv[j] = (f16)(v0[j] - (float)h0);
    f16 h1 = (f16)v1[j]; hv[j + 4] = h1; lv[j + 4] = (f16)(v1[j] - (float)h1);
  }
}

// ---------- prep: f32 in[R][C] -> tiled+swizzled fp16 hi/lo tiles ----------
__global__ __launch_bounds__(256) void k_prep(const float* __restrict__ in,
                                              f16* __restrict__ oh, f16* __restrict__ ol,
                                              int R, int C, int trShift) {
  __shared__ float t[64][65];
  int c0 = blockIdx.x * 64, r0 = blockIdx.y * 64;
  int tid = threadIdx.x;
#pragma unroll
  for (int i = 0; i < 16; ++i) {
    int idx = tid + i * 256;
    int r = idx >> 6, c = idx & 63;
    t[r][c] = in[(size_t)(r0 + r) * C + (c0 + c)];
  }
  __syncthreads();
  int ktiles = R >> 5;
  int TRm1 = (1 << trShift) - 1;
#pragma unroll
  for (int w = 0; w < 2; ++w) {
    int idx = tid + w * 256;
    int nn = idx >> 3, cc8 = idx & 7;
    f32x4 v0, v1;
#pragma unroll
    for (int j = 0; j < 4; ++j) v0[j] = t[cc8 * 8 + j][nn];
#pragma unroll
    for (int j = 0; j < 4; ++j) v1[j] = t[cc8 * 8 + 4 + j][nn];
    f16x8 hv, lv;
    split8n(v0, v1, hv, lv);
    int gn = c0 + nn, gk = r0 + cc8 * 8;
    size_t tileIdx = (size_t)(gn >> trShift) * ktiles + (gk >> 5);
    size_t off = (tileIdx << (trShift + 5)) + ((size_t)(gn & TRm1) << 5) +
                 (((cc8 & 3) ^ ((gn >> 1) & 3)) << 3);
    *(f16x8*)&oh[off] = hv;
    *(f16x8*)&ol[off] = lv;
  }
}

// ---------- GEMM1 v6b (best measured): 4 waves, wave = 32 rows x 128 cols ----------
// A direct-from-global f32 + in-reg split (no LDS); B 3-buf LDS, counted vmcnt.
// grid (64 bx, 2 nb, 4 kc), 1024 k per block, NS=32 steps.
__global__ __launch_bounds__(256, 3) void k_g1(
    const float* __restrict__ X, const f16* __restrict__ Bht,
    const f16* __restrict__ Blt, unsigned char* __restrict__ mb,
    float* __restrict__ partials) {
  __shared__ f16 smB[3][8192];  // [buf][h 0..4095 | l 4096..8191], 128n x 32k
  int bx = blockIdx.x, nb = blockIdx.y, kc = blockIdx.z;
  int tid = threadIdx.x;
  int wv = tid >> 6, ln = tid & 63, lr = ln & 15, lg = ln >> 4;
  const int NS = 32;
  int m0 = bx * 128, kb0 = kc * 1024;
  size_t bt0 = ((size_t)nb * 128 + (size_t)kc * 32) * 4096;
  bool domask = (nb == 0);

  const float* xb = X + (size_t)(m0 + wv * 32 + lr) * 4096 + kb0 + lg * 8;
  const size_t XF = (size_t)16 * 4096;

  f32x4 areg[4];
  f16x8 ah[2], al[2];
  f32x4 acc[2][8] = {};

  auto issueA = [&](int s) {
#pragma unroll
    for (int fi = 0; fi < 2; ++fi) {
      const float* p = xb + (size_t)fi * XF + s * 32;
      areg[fi * 2] = *(const f32x4*)p;
      areg[fi * 2 + 1] = *(const f32x4*)(p + 4);
    }
  };
  auto stageB = [&](int s, int buf) {
    const f16* bh = Bht + bt0 + (size_t)s * 4096;
    const f16* bl = Blt + bt0 + (size_t)s * 4096;
#pragma unroll
    for (int i = 0; i < 2; ++i)
      gload16(bh + ((i * 4 + wv) * 512 + ln * 8), &smB[buf][(i * 4 + wv) * 512]);
#pragma unroll
    for (int i = 0; i < 2; ++i)
      gload16(bl + ((i * 4 + wv) * 512 + ln * 8),
              &smB[buf][4096 + (i * 4 + wv) * 512]);
  };
  auto splitA = [&](int s) {
#pragma unroll
    for (int fi = 0; fi < 2; ++fi)
      split8n(areg[fi * 2], areg[fi * 2 + 1], ah[fi], al[fi]);
    if (domask) {
#pragma unroll
      for (int fi = 0; fi < 2; ++fi) {
        unsigned m = 0;
#pragma unroll
        for (int j = 0; j < 4; ++j) {
          if (areg[fi * 2][j] != 0.f) m |= 1u << j;
          if (areg[fi * 2 + 1][j] != 0.f) m |= 1u << (4 + j);
        }
        int row = m0 + wv * 32 + fi * 16 + lr;
        int gk = kb0 + s * 32 + lg * 8;
        mb[(size_t)row * 512 + (gk >> 3)] = (unsigned char)m;
      }
    }
  };

  issueA(0);
  stageB(0, 0);
  stageB(1, 1);
  asm volatile("s_waitcnt vmcnt(4)" ::: "memory");
  __builtin_amdgcn_sched_barrier(0);
  splitA(0);
  __builtin_amdgcn_s_barrier();

  int cb = 0;
  for (int s = 0; s < NS; ++s) {
    bool moreA = (s + 1) < NS;
    bool moreB = (s + 2) < NS;
    if (moreA) issueA(s + 1);
    if (moreB) {
      int pb = cb + 2; if (pb >= 3) pb -= 3;
      stageB(s + 2, pb);
    }
#pragma unroll
    for (int g = 0; g < 2; ++g) {
      f16x8 fbh[4], fbl[4];
#pragma unroll
      for (int j = 0; j < 4; ++j) {
        int c = (g * 4 + j) * 16 + lr;
        fbh[j] = *(const f16x8*)&smB[cb][swz(c, lg)];
        fbl[j] = *(const f16x8*)&smB[cb][4096 + swz(c, lg)];
      }
#pragma unroll
      for (int fi = 0; fi < 2; ++fi)
#pragma unroll
        for (int j = 0; j < 4; ++j) {
          acc[fi][g * 4 + j] = MFMA16(ah[fi], fbh[j], acc[fi][g * 4 + j]);
          acc[fi][g * 4 + j] = MFMA16(ah[fi], fbl[j], acc[fi][g * 4 + j]);
          acc[fi][g * 4 + j] = MFMA16(al[fi], fbh[j], acc[fi][g * 4 + j]);
        }
    }
    if (moreA) {
      if (moreB)
        asm volatile("s_waitcnt vmcnt(4)" ::: "memory");
      else
        asm volatile("s_waitcnt vmcnt(0)" ::: "memory");
      __builtin_amdgcn_sched_barrier(0);
      splitA(s + 1);
      __builtin_amdgcn_s_barrier();
    }
    cb = cb + 1; if (cb >= 3) cb -= 3;
  }

  float* pout = partials + (size_t)kc * 8192 * 256;
#pragma unroll
  for (int fi = 0; fi < 2; ++fi)
#pragma unroll
    for (int fj = 0; fj < 8; ++fj)
#pragma unroll
      for (int q = 0; q < 4; ++q) {
        int row = m0 + wv * 32 + fi * 16 + lg * 4 + q;
        int col = nb * 128 + fj * 16 + lr;
        pout[(size_t)row * 256 + col] = acc[fi][fj][q];
      }
}

// ---------- reduce split-K(4) + bias + relu + split -> tiled H hi/lo (TR=256) ----------
__global__ __launch_bounds__(256) void k_hsplit(const float* __restrict__ p,
                                                const float* __restrict__ b1,
                                                f16* __restrict__ Hh,
                                                f16* __restrict__ Hl) {
  int g = blockIdx.x * 256 + threadIdx.x;
  int r = g >> 5, c = g & 31;
  const size_t CH = (size_t)8192 * 256;
  const float* p0 = p + (size_t)r * 256 + c * 8;
  f32x4 s0 = *(const f32x4*)p0, s1 = *(const f32x4*)(p0 + 4);
#pragma unroll
  for (int q = 1; q < 4; ++q) {
    f32x4 d0 = *(const f32x4*)(p0 + q * CH), d1 = *(const f32x4*)(p0 + q * CH + 4);
#pragma unroll
    for (int j = 0; j < 4; ++j) { s0[j] += d0[j]; s1[j] += d1[j]; }
  }
  f32x4 bb0 = *(const f32x4*)(b1 + c * 8), bb1 = *(const f32x4*)(b1 + c * 8 + 4);
  f32x4 v0, v1;
#pragma unroll
  for (int j = 0; j < 4; ++j) {
    float v = s0[j] + bb0[j];
    v0[j] = v > 0.f ? v : 0.f;
    float w = s1[j] + bb1[j];
    v1[j] = w > 0.f ? w : 0.f;
  }
  f16x8 hv, lv;
  split8n(v0, v1, hv, lv);
  size_t tileIdx = (size_t)(r >> 8) * 8 + (c >> 2);
  size_t off = tileIdx * 8192 + ((size_t)(r & 255) << 5) +
               (((c & 3) ^ ((r >> 1) & 3)) << 3);
  *(f16x8*)&Hh[off] = hv;
  *(f16x8*)&Hl[off] = lv;
}

// ---------- GEMM2c: 256x256 tile, 8 waves, F = H @ W2 + b2, masked f16 store ----------
__global__ __launch_bounds__(512, 1) void k_gemm2c(
    const f16* __restrict__ At_h, const f16* __restrict__ At_l,
    const f16* __restrict__ Bt_h, const f16* __restrict__ Bt_l,
    const float* __restrict__ b2, const unsigned* __restrict__ maskw,
    f16* __restrict__ fout, float* __restrict__ partials) {
  __shared__ f16 smA[2][2][8192];
  __shared__ f16 smB[2][2][8192];
  __shared__ unsigned mlds[256][8];
  __shared__ float rsum[256][2];
  int bx = blockIdx.x, by = blockIdx.y;
  int m0 = bx * 256, n0 = by * 256;
  int tid = threadIdx.x;
  int wid = tid >> 6, ln = tid & 63, lr = ln & 15, lg = ln >> 4;
  int wr = wid >> 1, wc = wid & 1;
#pragma unroll
  for (int i = 0; i < 4; ++i) {
    int idx = tid + i * 512;
    mlds[idx >> 3][idx & 7] =
        maskw[(size_t)(m0 + (idx >> 3)) * 128 + by * 8 + (idx & 7)];
  }
  size_t at0 = (size_t)bx * 8 * 8192;
  size_t bt0 = (size_t)by * 8 * 8192;

  auto stage = [&](int s, int buf) {
#pragma unroll
    for (int i = 0; i < 2; ++i) {
      size_t o = (size_t)(i * 8 + wid) * 512 + (size_t)ln * 8;
      gload16(At_h + at0 + (size_t)s * 8192 + o, &smA[buf][0][(i * 8 + wid) * 512]);
      gload16(At_l + at0 + (size_t)s * 8192 + o, &smA[buf][1][(i * 8 + wid) * 512]);
      gload16(Bt_h + bt0 + (size_t)s * 8192 + o, &smB[buf][0][(i * 8 + wid) * 512]);
      gload16(Bt_l + bt0 + (size_t)s * 8192 + o, &smB[buf][1][(i * 8 + wid) * 512]);
    }
  };

  f32x4 acc[4][8] = {};
  stage(0, 0);
  __syncthreads();
  int cur = 0;
  for (int s = 0; s < 8; ++s) {
    if (s + 1 < 8) stage(s + 1, cur ^ 1);
    f16x8 fah[4], fal[4];
#pragma unroll
    for (int f = 0; f < 4; ++f) {
      int r = wr * 64 + f * 16 + lr;
      fah[f] = *(const f16x8*)&smA[cur][0][swz(r, lg)];
      fal[f] = *(const f16x8*)&smA[cur][1][swz(r, lg)];
    }
#pragma unroll
    for (int g = 0; g < 2; ++g) {
      f16x8 fbh[4], fbl[4];
#pragma unroll
      for (int j = 0; j < 4; ++j) {
        int c = wc * 128 + (g * 4 + j) * 16 + lr;
        fbh[j] = *(const f16x8*)&smB[cur][0][swz(c, lg)];
        fbl[j] = *(const f16x8*)&smB[cur][1][swz(c, lg)];
      }
#pragma unroll
      for (int fi = 0; fi < 4; ++fi)
#pragma unroll
        for (int j = 0; j < 4; ++j) {
          acc[fi][g * 4 + j] = MFMA16(fah[fi], fbh[j], acc[fi][g * 4 + j]);
          acc[fi][g * 4 + j] = MFMA16(fah[fi], fbl[j], acc[fi][g * 4 + j]);
          acc[fi][g * 4 + j] = MFMA16(fal[fi], fbh[j], acc[fi][g * 4 + j]);
        }
    }
    __syncthreads();
    cur ^= 1;
  }

  float rp[4][4] = {};
#pragma unroll
  for (int fi = 0; fi < 4; ++fi)
#pragma unroll
    for (int fj = 0; fj < 8; ++fj)
#pragma unroll
      for (int q = 0; q < 4; ++q) {
        int row = wr * 64 + fi * 16 + lg * 4 + q;
        int col = wc * 128 + fj * 16 + lr;
        float v = acc[fi][fj][q] + b2[n0 + col];
        unsigned wd = mlds[row][col >> 5];
        float mv = ((wd >> (col & 31)) & 1u) ? v : 0.f;
        fout[(size_t)(m0 + row) * 4096 + (n0 + col)] = (f16)mv;
        rp[fi][q] += mv;
      }
#pragma unroll
  for (int fi = 0; fi < 4; ++fi)
#pragma unroll
    for (int q = 0; q < 4; ++q) {
      float sv = rp[fi][q];
      sv += __shfl_xor(sv, 1);
      sv += __shfl_xor(sv, 2);
      sv += __shfl_xor(sv, 4);
      sv += __shfl_xor(sv, 8);
      if (lr == 0) rsum[wr * 64 + fi * 16 + lg * 4 + q][wc] = sv;
    }
  __syncthreads();
  if (tid < 256)
    partials[(size_t)(m0 + tid) * 16 + by] = rsum[tid][0] + rsum[tid][1];
}

// ---------- scale: f16 f * (1/rowsum) -> f32 out; rowinv fused in-block ----------
// each block covers 2048 consecutive f16 = exactly half of one row
__global__ __launch_bounds__(256) void k_scale16(const f16* __restrict__ f,
                                                 const float* __restrict__ partials,
                                                 float* __restrict__ out) {
  __shared__ float sinv;
  int tid = threadIdx.x;
  int row = blockIdx.x >> 1;
  if (tid == 0) {
    float s = 0.f;
#pragma unroll
    for (int i = 0; i < 16; ++i) s += partials[(size_t)row * 16 + i];
    sinv = 1.f / ((s == 0.f) ? 1.f : s);
  }
  __syncthreads();
  float iv = sinv;
  size_t v = (size_t)blockIdx.x * 256 + tid;
  f16x8 d = *(const f16x8*)(f + v * 8);
  f32x4 o0, o1;
#pragma unroll
  for (int j = 0; j < 4; ++j) {
    o0[j] = (float)d[j] * iv;
    o1[j] = (float)d[4 + j] * iv;
  }
  *(f32x4*)(out + v * 8) = o0;
  *(f32x4*)(out + v * 8 + 4) = o1;
}

extern "C" void kernel_launch(void* const* d_in, const int* in_sizes, int n_in,
                              void* d_out, int out_size, void* d_ws, size_t ws_size,
                              hipStream_t stream) {
  const float* x  = (const float*)d_in[0];
  const float* W1 = (const float*)d_in[1];
  const float* b1 = (const float*)d_in[2];
  const float* W2 = (const float*)d_in[3];
  const float* b2 = (const float*)d_in[4];
  float* out = (float*)d_out;
  char* ws = (char*)d_ws;

  const size_t MB = (size_t)1 << 20;
  f16* W1t_h = (f16*)(ws + 0 * MB);    // 2 MB, TR=128 tiles (gemm1 B)
  f16* W1t_l = (f16*)(ws + 2 * MB);
  f16* W2t_h = (f16*)(ws + 4 * MB);    // 2 MB, TR=256 tiles (gemm2 B)
  f16* W2t_l = (f16*)(ws + 6 * MB);
  f16* Hh    = (f16*)(ws + 8 * MB);    // 4 MB, TR=256 tiles (gemm2 A)
  f16* Hl    = (f16*)(ws + 12 * MB);
  unsigned char* mb = (unsigned char*)(ws + 16 * MB);  // 4 MB
  float* part1 = (float*)(ws + 20 * MB);   // 32 MB (4 x 8 MB split-K)
  float* part2 = (float*)(ws + 52 * MB);   // 512 KB [8192][16]
  f16* fbuf    = (f16*)(ws + 54 * MB);     // 64 MB f16 f-buffer

  k_prep<<<dim3(4, 64), 256, 0, stream>>>(W1, W1t_h, W1t_l, 4096, 256, 7);
  k_prep<<<dim3(64, 4), 256, 0, stream>>>(W2, W2t_h, W2t_l, 256, 4096, 8);
  k_g1<<<dim3(64, 2, 4), 256, 0, stream>>>(x, W1t_h, W1t_l, mb, part1);
  k_hsplit<<<1024, 256, 0, stream>>>(part1, b1, Hh, Hl);
  k_gemm2c<<<dim3(32, 16), 512, 0, stream>>>(Hh, Hl, W2t_h, W2t_l, b2,
                                             (const unsigned*)mb, fbuf, part2);
  k_scale16<<<16384, 256, 0, stream>>>(fbuf, part2, out);
}